// Round 1
// baseline (25287.653 us; speedup 1.0000x reference)
//
#include <hip/hip_runtime.h>
#include <hip/hip_bf16.h>

// TransformerNMT: B=8, S=T=512, D=512, H=8, hd=64, L=6, DFF=2048, V=32000, PAD=0
// Round 0: all-f32 correctness-first implementation.
//   - embed+PE fused kernel
//   - tiled f32 GEMM (128x128x16, 8x8/thread) with bias (+optional ReLU)
//   - attention: block per (b,h,16 q-rows); K/V staged in LDS; full score row in LDS
//   - fused residual + LayerNorm (in-place on the stream buffer)

#define Dm 512
#define Hh 8
#define HD 64
#define Ll 6
#define DFFv 2048
#define Vv 32000
#define Bb 8
#define Ss 512
#define NTOK (Bb * Ss)   // 4096 rows

// ---------------------------------------------------------------- embed + PE
__global__ void embed_pe_k(const int* __restrict__ tok, const float* __restrict__ emb,
                           float* __restrict__ out, int Slen)
{
    int row = blockIdx.x;                 // b*Slen + s
    int s = row % Slen;
    int t = tok[row];
    const float* e = emb + (size_t)t * Dm;
    float* o = out + (size_t)row * Dm;
    for (int dd = threadIdx.x; dd < Dm; dd += blockDim.x) {
        int j = dd >> 1;
        // div = exp(2j * (-ln(10000)/512))
        float div = expf((float)(2 * j) * (-9.210340371976184f / 512.0f));
        float ang = (float)s * div;
        float pe = (dd & 1) ? cosf(ang) : sinf(ang);
        o[dd] = e[dd] * 22.627416997969522f + pe;   // sqrt(512)
    }
}

// ---------------------------------------------------------------- f32 GEMM
// C[M,N] = A[M,K] @ W[K,N] + bias[N], optional ReLU. M%128==0, N%128==0, K%16==0.
template<int RELU>
__global__ __launch_bounds__(256) void gemm_f32_k(const float* __restrict__ A,
                                                  const float* __restrict__ W,
                                                  const float* __restrict__ bias,
                                                  float* __restrict__ C,
                                                  int M, int N, int K)
{
    __shared__ float As[16][132];   // [k][m], padded (528B row: 16B aligned)
    __shared__ float Bs[16][128];   // [k][n]
    int tid = threadIdx.x;
    int tx = tid & 15, ty = tid >> 4;
    int row0 = blockIdx.y * 128;
    int col0 = blockIdx.x * 128;
    float acc[8][8] = {};

    for (int k0 = 0; k0 < K; k0 += 16) {
        // A tile: 128 rows x 16 k  (512 float4 chunks, 2/thread, row-coalesced)
        #pragma unroll
        for (int c = 0; c < 2; ++c) {
            int ch = c * 256 + tid;          // 0..511
            int m = ch >> 2;                 // 0..127
            int kq = (ch & 3) * 4;           // 0,4,8,12
            float4 a4 = *reinterpret_cast<const float4*>(
                &A[(size_t)(row0 + m) * K + k0 + kq]);
            As[kq + 0][m] = a4.x; As[kq + 1][m] = a4.y;
            As[kq + 2][m] = a4.z; As[kq + 3][m] = a4.w;
        }
        // B tile: 16 k x 128 n (2 float4 per thread, contiguous)
        {
            int n0 = tx * 8;
            const float* wp = &W[(size_t)(k0 + ty) * N + col0 + n0];
            *reinterpret_cast<float4*>(&Bs[ty][n0])     = *reinterpret_cast<const float4*>(wp);
            *reinterpret_cast<float4*>(&Bs[ty][n0 + 4]) = *reinterpret_cast<const float4*>(wp + 4);
        }
        __syncthreads();
        #pragma unroll
        for (int k = 0; k < 16; ++k) {
            float a[8], b[8];
            *reinterpret_cast<float4*>(&a[0]) = *reinterpret_cast<const float4*>(&As[k][ty * 8]);
            *reinterpret_cast<float4*>(&a[4]) = *reinterpret_cast<const float4*>(&As[k][ty * 8 + 4]);
            *reinterpret_cast<float4*>(&b[0]) = *reinterpret_cast<const float4*>(&Bs[k][tx * 8]);
            *reinterpret_cast<float4*>(&b[4]) = *reinterpret_cast<const float4*>(&Bs[k][tx * 8 + 4]);
            #pragma unroll
            for (int i = 0; i < 8; ++i)
                #pragma unroll
                for (int j = 0; j < 8; ++j)
                    acc[i][j] += a[i] * b[j];
        }
        __syncthreads();
    }

    // epilogue: bias (+relu), float4 stores
    #pragma unroll
    for (int i = 0; i < 8; ++i) {
        size_t r = (size_t)(row0 + ty * 8 + i);
        #pragma unroll
        for (int j = 0; j < 8; j += 4) {
            int cidx = col0 + tx * 8 + j;
            float4 v;
            v.x = acc[i][j + 0] + bias[cidx + 0];
            v.y = acc[i][j + 1] + bias[cidx + 1];
            v.z = acc[i][j + 2] + bias[cidx + 2];
            v.w = acc[i][j + 3] + bias[cidx + 3];
            if (RELU) {
                v.x = fmaxf(v.x, 0.f); v.y = fmaxf(v.y, 0.f);
                v.z = fmaxf(v.z, 0.f); v.w = fmaxf(v.w, 0.f);
            }
            *reinterpret_cast<float4*>(&C[r * N + cidx]) = v;
        }
    }
}

// ---------------------------------------------------------------- attention
// Q,K,V,O: [B*S, 512] row-major, head h at cols h*64..h*64+63.
// Block: 256 threads, handles 16 q-rows of one (b,h). key_tok: pad mask tokens
// (mask out where tok==0); causal: also mask k>q.
__global__ __launch_bounds__(256) void attn_k(const float* __restrict__ Q,
                                              const float* __restrict__ Kp,
                                              const float* __restrict__ Vp,
                                              float* __restrict__ O,
                                              const int* __restrict__ key_tok,
                                              int Sq, int Sk, int causal)
{
    __shared__ float qs[16][64];
    __shared__ float sc[16][516];   // padded
    __shared__ float kv[64][68];    // padded (272B row: 16B aligned)
    __shared__ float invs[16];

    int tid = threadIdx.x;
    int q0 = blockIdx.x * 16;
    int h = blockIdx.y, b = blockIdx.z;
    const int hoff = h * HD;

    // load Q tile (1024 floats, 4/thread)
    {
        int idx = tid * 4;
        int qi = idx >> 6, d = idx & 63;
        *reinterpret_cast<float4*>(&qs[qi][d]) = *reinterpret_cast<const float4*>(
            &Q[((size_t)(b * Sq + q0 + qi)) * Dm + hoff + d]);
    }

    // ---- scores
    for (int kk0 = 0; kk0 < Sk; kk0 += 64) {
        __syncthreads();
        #pragma unroll
        for (int c = 0; c < 4; ++c) {
            int ch = c * 256 + tid;          // 0..1023
            int r = ch >> 4, dq = (ch & 15) * 4;
            *reinterpret_cast<float4*>(&kv[r][dq]) = *reinterpret_cast<const float4*>(
                &Kp[((size_t)(b * Sk + kk0 + r)) * Dm + hoff + dq]);
        }
        __syncthreads();
        #pragma unroll
        for (int rr = 0; rr < 4; ++rr) {
            int idx = rr * 256 + tid;
            int qi = idx & 15, kk = idx >> 4;   // kk 0..63
            float s = 0.f;
            #pragma unroll
            for (int i = 0; i < 64; i += 4) {
                float4 q4 = *reinterpret_cast<const float4*>(&qs[qi][i]);
                float4 k4 = *reinterpret_cast<const float4*>(&kv[kk][i]);
                s += q4.x * k4.x + q4.y * k4.y + q4.z * k4.z + q4.w * k4.w;
            }
            int kkg = kk0 + kk;
            bool valid = true;
            if (key_tok) valid = (key_tok[(size_t)b * Sk + kkg] != 0);
            if (causal && kkg > q0 + qi) valid = false;
            sc[qi][kkg] = valid ? s * 0.125f : -1e9f;   // 1/sqrt(64)
        }
    }
    __syncthreads();

    // ---- softmax per q-row (16 lanes per row, all within one wave group)
    {
        int qi = tid >> 4, tx = tid & 15;
        float m = -3.0e38f;
        for (int kk = tx; kk < Sk; kk += 16) m = fmaxf(m, sc[qi][kk]);
        #pragma unroll
        for (int o = 1; o < 16; o <<= 1) m = fmaxf(m, __shfl_xor(m, o));
        float sum = 0.f;
        for (int kk = tx; kk < Sk; kk += 16) {
            float p = __expf(sc[qi][kk] - m);
            sc[qi][kk] = p;
            sum += p;
        }
        #pragma unroll
        for (int o = 1; o < 16; o <<= 1) sum += __shfl_xor(sum, o);
        if (tx == 0) invs[qi] = 1.0f / sum;
    }

    // ---- ctx = P @ V
    float acc0 = 0.f, acc1 = 0.f, acc2 = 0.f, acc3 = 0.f;
    int d = tid & 63, qg = tid >> 6;   // wave-uniform qg
    for (int kk0 = 0; kk0 < Sk; kk0 += 64) {
        __syncthreads();   // also guards softmax sc/invs writes on first iter
        #pragma unroll
        for (int c = 0; c < 4; ++c) {
            int ch = c * 256 + tid;
            int r = ch >> 4, dq = (ch & 15) * 4;
            *reinterpret_cast<float4*>(&kv[r][dq]) = *reinterpret_cast<const float4*>(
                &Vp[((size_t)(b * Sk + kk0 + r)) * Dm + hoff + dq]);
        }
        __syncthreads();
        #pragma unroll
        for (int kk = 0; kk < 64; ++kk) {
            float vv = kv[kk][d];
            acc0 += sc[qg * 4 + 0][kk0 + kk] * vv;
            acc1 += sc[qg * 4 + 1][kk0 + kk] * vv;
            acc2 += sc[qg * 4 + 2][kk0 + kk] * vv;
            acc3 += sc[qg * 4 + 3][kk0 + kk] * vv;
        }
    }
    O[((size_t)(b * Sq + q0 + qg * 4 + 0)) * Dm + hoff + d] = acc0 * invs[qg * 4 + 0];
    O[((size_t)(b * Sq + q0 + qg * 4 + 1)) * Dm + hoff + d] = acc1 * invs[qg * 4 + 1];
    O[((size_t)(b * Sq + q0 + qg * 4 + 2)) * Dm + hoff + d] = acc2 * invs[qg * 4 + 2];
    O[((size_t)(b * Sq + q0 + qg * 4 + 3)) * Dm + hoff + d] = acc3 * invs[qg * 4 + 3];
}

// ---------------------------------------------------------------- residual + LN (in-place)
__global__ __launch_bounds__(256) void add_ln_k(float* __restrict__ x,
                                                const float* __restrict__ a,
                                                const float* __restrict__ g,
                                                const float* __restrict__ bb)
{
    int row = blockIdx.x;
    size_t base = (size_t)row * Dm;
    int tid = threadIdx.x;
    float v0 = x[base + tid]       + a[base + tid];
    float v1 = x[base + tid + 256] + a[base + tid + 256];
    float s  = v0 + v1;
    float s2 = v0 * v0 + v1 * v1;
    #pragma unroll
    for (int o = 1; o < 64; o <<= 1) {
        s  += __shfl_xor(s, o);
        s2 += __shfl_xor(s2, o);
    }
    __shared__ float red[8];
    int wid = tid >> 6, lane = tid & 63;
    if (lane == 0) { red[wid] = s; red[wid + 4] = s2; }
    __syncthreads();
    s  = red[0] + red[1] + red[2] + red[3];
    s2 = red[4] + red[5] + red[6] + red[7];
    float mean = s * (1.0f / 512.0f);
    float var  = s2 * (1.0f / 512.0f) - mean * mean;
    float rstd = rsqrtf(var + 1e-5f);
    x[base + tid]       = (v0 - mean) * rstd * g[tid]       + bb[tid];
    x[base + tid + 256] = (v1 - mean) * rstd * g[tid + 256] + bb[tid + 256];
}

// ---------------------------------------------------------------- launch
extern "C" void kernel_launch(void* const* d_in, const int* in_sizes, int n_in,
                              void* d_out, int out_size, void* d_ws, size_t ws_size,
                              hipStream_t stream)
{
    const int*   src        = (const int*)  d_in[0];
    const int*   tgt        = (const int*)  d_in[1];
    const float* src_emb    = (const float*)d_in[2];
    const float* tgt_emb    = (const float*)d_in[3];
    const float* enc_attn_w = (const float*)d_in[4];
    const float* enc_attn_b = (const float*)d_in[5];
    const float* enc_ffn_w1 = (const float*)d_in[6];
    const float* enc_ffn_b1 = (const float*)d_in[7];
    const float* enc_ffn_w2 = (const float*)d_in[8];
    const float* enc_ffn_b2 = (const float*)d_in[9];
    const float* enc_ln_g   = (const float*)d_in[10];
    const float* enc_ln_b   = (const float*)d_in[11];
    const float* dec_self_w = (const float*)d_in[12];
    const float* dec_self_b = (const float*)d_in[13];
    const float* dec_cross_w= (const float*)d_in[14];
    const float* dec_cross_b= (const float*)d_in[15];
    const float* dec_ffn_w1 = (const float*)d_in[16];
    const float* dec_ffn_b1 = (const float*)d_in[17];
    const float* dec_ffn_w2 = (const float*)d_in[18];
    const float* dec_ffn_b2 = (const float*)d_in[19];
    const float* dec_ln_g   = (const float*)d_in[20];
    const float* dec_ln_b   = (const float*)d_in[21];
    const float* out_w      = (const float*)d_in[22];
    const float* out_b      = (const float*)d_in[23];

    const size_t NROW = (size_t)NTOK * Dm;   // 2,097,152 floats
    float* ws  = (float*)d_ws;
    float* xe  = ws;            // encoder stream  [4096,512]
    float* xd  = xe + NROW;     // decoder stream
    float* qb  = xd + NROW;
    float* kb  = qb + NROW;
    float* vb  = kb + NROW;
    float* ctx = vb + NROW;
    float* t0  = ctx + NROW;
    float* h1  = t0 + NROW;     // FFN hidden [4096,2048]

    auto gemm = [&](const float* A, const float* W, const float* bias, float* C,
                    int M, int N, int K, bool relu) {
        dim3 grid(N / 128, M / 128);
        if (relu) gemm_f32_k<1><<<grid, 256, 0, stream>>>(A, W, bias, C, M, N, K);
        else      gemm_f32_k<0><<<grid, 256, 0, stream>>>(A, W, bias, C, M, N, K);
    };
    auto attn = [&](const float* Q, const float* K, const float* V, float* O,
                    const int* kt, int causal) {
        attn_k<<<dim3(Ss / 16, Hh, Bb), 256, 0, stream>>>(Q, K, V, O, kt, Ss, Ss, causal);
    };
    auto lnorm = [&](float* x, const float* a, const float* g, const float* b) {
        add_ln_k<<<NTOK, 256, 0, stream>>>(x, a, g, b);
    };

    // embeddings + PE
    embed_pe_k<<<NTOK, 256, 0, stream>>>(src, src_emb, xe, Ss);
    embed_pe_k<<<NTOK, 256, 0, stream>>>(tgt, tgt_emb, xd, Ss);

    const size_t WSZ = (size_t)Dm * Dm;          // 262144
    // ---------------- encoder
    for (int i = 0; i < Ll; ++i) {
        const float* W  = enc_attn_w + (size_t)i * 4 * WSZ;
        const float* Bv = enc_attn_b + (size_t)i * 4 * Dm;
        gemm(xe, W + 0 * WSZ, Bv + 0 * Dm, qb, NTOK, Dm, Dm, false);
        gemm(xe, W + 1 * WSZ, Bv + 1 * Dm, kb, NTOK, Dm, Dm, false);
        gemm(xe, W + 2 * WSZ, Bv + 2 * Dm, vb, NTOK, Dm, Dm, false);
        attn(qb, kb, vb, ctx, src, 0);
        gemm(ctx, W + 3 * WSZ, Bv + 3 * Dm, t0, NTOK, Dm, Dm, false);
        lnorm(xe, t0, enc_ln_g + i * 2 * Dm, enc_ln_b + i * 2 * Dm);
        gemm(xe, enc_ffn_w1 + (size_t)i * Dm * DFFv, enc_ffn_b1 + i * DFFv, h1, NTOK, DFFv, Dm, true);
        gemm(h1, enc_ffn_w2 + (size_t)i * DFFv * Dm, enc_ffn_b2 + i * Dm, t0, NTOK, Dm, DFFv, false);
        lnorm(xe, t0, enc_ln_g + i * 2 * Dm + Dm, enc_ln_b + i * 2 * Dm + Dm);
    }

    // ---------------- decoder
    for (int i = 0; i < Ll; ++i) {
        const float* Wsf = dec_self_w + (size_t)i * 4 * WSZ;
        const float* Bsf = dec_self_b + (size_t)i * 4 * Dm;
        gemm(xd, Wsf + 0 * WSZ, Bsf + 0 * Dm, qb, NTOK, Dm, Dm, false);
        gemm(xd, Wsf + 1 * WSZ, Bsf + 1 * Dm, kb, NTOK, Dm, Dm, false);
        gemm(xd, Wsf + 2 * WSZ, Bsf + 2 * Dm, vb, NTOK, Dm, Dm, false);
        attn(qb, kb, vb, ctx, tgt, 1);                       // causal + tgt pad
        gemm(ctx, Wsf + 3 * WSZ, Bsf + 3 * Dm, t0, NTOK, Dm, Dm, false);
        lnorm(xd, t0, dec_ln_g + i * 3 * Dm, dec_ln_b + i * 3 * Dm);

        const float* Wc = dec_cross_w + (size_t)i * 4 * WSZ;
        const float* Bc = dec_cross_b + (size_t)i * 4 * Dm;
        gemm(xd, Wc + 0 * WSZ, Bc + 0 * Dm, qb, NTOK, Dm, Dm, false);
        gemm(xe, Wc + 1 * WSZ, Bc + 1 * Dm, kb, NTOK, Dm, Dm, false);   // K from memory
        gemm(xe, Wc + 2 * WSZ, Bc + 2 * Dm, vb, NTOK, Dm, Dm, false);   // V from memory
        attn(qb, kb, vb, ctx, src, 0);                       // src pad
        gemm(ctx, Wc + 3 * WSZ, Bc + 3 * Dm, t0, NTOK, Dm, Dm, false);
        lnorm(xd, t0, dec_ln_g + i * 3 * Dm + Dm, dec_ln_b + i * 3 * Dm + Dm);

        gemm(xd, dec_ffn_w1 + (size_t)i * Dm * DFFv, dec_ffn_b1 + i * DFFv, h1, NTOK, DFFv, Dm, true);
        gemm(h1, dec_ffn_w2 + (size_t)i * DFFv * Dm, dec_ffn_b2 + i * Dm, t0, NTOK, Dm, DFFv, false);
        lnorm(xd, t0, dec_ln_g + i * 3 * Dm + 2 * Dm, dec_ln_b + i * 3 * Dm + 2 * Dm);
    }

    // ---------------- final vocab projection -> d_out [8,512,32000] f32
    gemm(xd, out_w, out_b, (float*)d_out, NTOK, Vv, Dm, false);
}

// Round 2
// 13273.080 us; speedup vs baseline: 1.9052x; 1.9052x over previous
//
#include <hip/hip_runtime.h>
#include <hip/hip_bf16.h>

// TransformerNMT r1: bf16 MFMA GEMMs (m97-style 2-barrier, global_load_lds w16),
// f32 residual/LN/softmax/attention. Weights transposed+converted per call.
// B=8, S=T=512, D=512, H=8, hd=64, L=6, DFF=2048, V=32000, PAD=0

#define Dm 512
#define Hh 8
#define HD 64
#define Ll 6
#define DFFv 2048
#define Vv 32000
#define Bb 8
#define Ss 512
#define NTOK (Bb * Ss)   // 4096 rows

typedef __bf16 bf16x8 __attribute__((ext_vector_type(8)));
typedef __bf16 bf16x4 __attribute__((ext_vector_type(4)));
typedef float  f32x4  __attribute__((ext_vector_type(4)));

#define GLOAD16(gp, lp) __builtin_amdgcn_global_load_lds( \
    (const __attribute__((address_space(1))) unsigned int*)(const void*)(gp), \
    (__attribute__((address_space(3))) unsigned int*)(void*)(lp), 16, 0, 0)

// ---------------------------------------------------------------- embed + PE (f32 + bf16 out)
__global__ void embed_pe_k(const int* __restrict__ tok, const float* __restrict__ emb,
                           float* __restrict__ out, __bf16* __restrict__ outb, int Slen)
{
    int row = blockIdx.x;
    int s = row % Slen;
    int t = tok[row];
    const float* e = emb + (size_t)t * Dm;
    float* o = out + (size_t)row * Dm;
    __bf16* ob = outb + (size_t)row * Dm;
    for (int dd = threadIdx.x; dd < Dm; dd += blockDim.x) {
        int j = dd >> 1;
        float div = expf((float)(2 * j) * (-9.210340371976184f / 512.0f));
        float ang = (float)s * div;
        float pe = (dd & 1) ? cosf(ang) : sinf(ang);
        float v = e[dd] * 22.627416997969522f + pe;   // sqrt(512)
        o[dd] = v;
        ob[dd] = (__bf16)v;
    }
}

// ---------------------------------------------------------------- weight transpose+convert
// W [K,N] f32 -> Wt [N,K] bf16, per matrix (blockIdx.z)
__global__ __launch_bounds__(256) void wtr_k(const float* __restrict__ W,
                                             __bf16* __restrict__ Wt, int K, int N)
{
    __shared__ float t[32][33];
    size_t msz = (size_t)K * N;
    const float* Wm = W + (size_t)blockIdx.z * msz;
    __bf16* Wtm = Wt + (size_t)blockIdx.z * msz;
    int n0 = blockIdx.x * 32, k0 = blockIdx.y * 32;
    int r = threadIdx.x >> 3, c4 = (threadIdx.x & 7) * 4;
    float4 v = *reinterpret_cast<const float4*>(&Wm[(size_t)(k0 + r) * N + n0 + c4]);
    t[r][c4] = v.x; t[r][c4 + 1] = v.y; t[r][c4 + 2] = v.z; t[r][c4 + 3] = v.w;
    __syncthreads();
    int n = threadIdx.x >> 3, kq = (threadIdx.x & 7) * 4;
    bf16x4 o;
    o[0] = (__bf16)t[kq + 0][n]; o[1] = (__bf16)t[kq + 1][n];
    o[2] = (__bf16)t[kq + 2][n]; o[3] = (__bf16)t[kq + 3][n];
    *reinterpret_cast<bf16x4*>(&Wtm[(size_t)(n0 + n) * K + k0 + kq]) = o;
}

// ---------------------------------------------------------------- f32 -> bf16 convert
__global__ void cvt_bf16_k(const float* __restrict__ in, __bf16* __restrict__ out, int n)
{
    int i = (blockIdx.x * 256 + threadIdx.x) * 8;
    if (i >= n) return;
    float4 a = *reinterpret_cast<const float4*>(&in[i]);
    float4 b = *reinterpret_cast<const float4*>(&in[i + 4]);
    bf16x8 v;
    v[0] = (__bf16)a.x; v[1] = (__bf16)a.y; v[2] = (__bf16)a.z; v[3] = (__bf16)a.w;
    v[4] = (__bf16)b.x; v[5] = (__bf16)b.y; v[6] = (__bf16)b.z; v[7] = (__bf16)b.w;
    *reinterpret_cast<bf16x8*>(&out[i]) = v;
}

// ---------------------------------------------------------------- MFMA GEMM
// C[M,N] = A[M,K](bf16) @ Wt[N,K](bf16)^T + bias, opt ReLU, out f32 or bf16.
// Block 256 thr = 4 waves (2x2), tile 128 x BN, BK=32. m97-style 2-barrier loop.
template<int BN, int RELU, int OUTBF16>
__global__ __launch_bounds__(256) void gemm_mfma_k(const __bf16* __restrict__ A,
                                                   const __bf16* __restrict__ Wt,
                                                   const float* __restrict__ bias,
                                                   void* __restrict__ Cout,
                                                   int M, int N, int K)
{
    constexpr int NF_N = BN / 32;   // fragments per wave in N: 128->4, 64->2
    constexpr int WCS  = BN / 2;    // wave column stride
    __shared__ __bf16 As[128 * 32];
    __shared__ __bf16 Bs[BN * 32];
    const int tid = threadIdx.x;
    const int wave = tid >> 6, lane = tid & 63;
    const int wr = wave >> 1, wc = wave & 1;
    const int row0 = blockIdx.y * 128, col0 = blockIdx.x * BN;

    f32x4 acc[4][NF_N] = {};

    const int rsub = lane >> 2;          // 0..15 (row within 16-row chunk)
    const int kel  = (lane & 3) * 8;     // k element offset (16B granule)
    const int fr   = lane & 15;          // fragment row/col
    const int kg   = lane >> 4;          // k-group 0..3

    for (int k0 = 0; k0 < K; k0 += 32) {
        // stage A-tile (128x32): 8 chunks of 16 rows, 2 per wave
        #pragma unroll
        for (int cc = 0; cc < 2; ++cc) {
            int c = wave * 2 + cc;
            int row = c * 16 + rsub;
            GLOAD16(A + (size_t)(row0 + row) * K + k0 + kel,
                    As + c * 512 + lane * 8);
        }
        // stage B-tile (BN x 32)
        if constexpr (BN == 128) {
            #pragma unroll
            for (int cc = 0; cc < 2; ++cc) {
                int c = wave * 2 + cc;
                int row = c * 16 + rsub;
                GLOAD16(Wt + (size_t)(col0 + row) * K + k0 + kel,
                        Bs + c * 512 + lane * 8);
            }
        } else {
            int c = wave;
            int row = c * 16 + rsub;
            GLOAD16(Wt + (size_t)(col0 + row) * K + k0 + kel,
                    Bs + c * 512 + lane * 8);
        }
        __syncthreads();   // drains vmcnt before barrier -> tiles ready

        const bf16x8* Av = reinterpret_cast<const bf16x8*>(As);
        const bf16x8* Bv = reinterpret_cast<const bf16x8*>(Bs);
        bf16x8 af[4], bq[NF_N];
        #pragma unroll
        for (int m = 0; m < 4; ++m)
            af[m] = Av[(wr * 64 + m * 16 + fr) * 4 + kg];
        #pragma unroll
        for (int n = 0; n < NF_N; ++n)
            bq[n] = Bv[(wc * WCS + n * 16 + fr) * 4 + kg];
        #pragma unroll
        for (int m = 0; m < 4; ++m)
            #pragma unroll
            for (int n = 0; n < NF_N; ++n)
                acc[m][n] = __builtin_amdgcn_mfma_f32_16x16x32_bf16(
                    af[m], bq[n], acc[m][n], 0, 0, 0);
        __syncthreads();   // all reads done before next stage overwrites
    }

    // epilogue: D row = (lane>>4)*4 + j, col = lane&15 (m89-verified layout)
    #pragma unroll
    for (int m = 0; m < 4; ++m) {
        #pragma unroll
        for (int n = 0; n < NF_N; ++n) {
            int col = col0 + wc * WCS + n * 16 + fr;
            float bv = bias[col];
            #pragma unroll
            for (int j = 0; j < 4; ++j) {
                int row = row0 + wr * 64 + m * 16 + kg * 4 + j;
                float v = acc[m][n][j] + bv;
                if (RELU) v = fmaxf(v, 0.f);
                if (OUTBF16)
                    ((__bf16*)Cout)[(size_t)row * N + col] = (__bf16)v;
                else
                    ((float*)Cout)[(size_t)row * N + col] = v;
            }
        }
    }
}

// ---------------------------------------------------------------- attention (f32)
__global__ __launch_bounds__(256) void attn_k(const float* __restrict__ Q,
                                              const float* __restrict__ Kp,
                                              const float* __restrict__ Vp,
                                              float* __restrict__ O,
                                              const int* __restrict__ key_tok,
                                              int Sq, int Sk, int causal)
{
    __shared__ float qs[16][64];
    __shared__ float sc[16][516];
    __shared__ float kv[64][68];
    __shared__ float invs[16];

    int tid = threadIdx.x;
    int q0 = blockIdx.x * 16;
    int h = blockIdx.y, b = blockIdx.z;
    const int hoff = h * HD;

    {
        int idx = tid * 4;
        int qi = idx >> 6, d = idx & 63;
        *reinterpret_cast<float4*>(&qs[qi][d]) = *reinterpret_cast<const float4*>(
            &Q[((size_t)(b * Sq + q0 + qi)) * Dm + hoff + d]);
    }

    for (int kk0 = 0; kk0 < Sk; kk0 += 64) {
        __syncthreads();
        #pragma unroll
        for (int c = 0; c < 4; ++c) {
            int ch = c * 256 + tid;
            int r = ch >> 4, dq = (ch & 15) * 4;
            *reinterpret_cast<float4*>(&kv[r][dq]) = *reinterpret_cast<const float4*>(
                &Kp[((size_t)(b * Sk + kk0 + r)) * Dm + hoff + dq]);
        }
        __syncthreads();
        #pragma unroll
        for (int rr = 0; rr < 4; ++rr) {
            int idx = rr * 256 + tid;
            int qi = idx & 15, kk = idx >> 4;
            float s = 0.f;
            #pragma unroll
            for (int i = 0; i < 64; i += 4) {
                float4 q4 = *reinterpret_cast<const float4*>(&qs[qi][i]);
                float4 k4 = *reinterpret_cast<const float4*>(&kv[kk][i]);
                s += q4.x * k4.x + q4.y * k4.y + q4.z * k4.z + q4.w * k4.w;
            }
            int kkg = kk0 + kk;
            bool valid = true;
            if (key_tok) valid = (key_tok[(size_t)b * Sk + kkg] != 0);
            if (causal && kkg > q0 + qi) valid = false;
            sc[qi][kkg] = valid ? s * 0.125f : -1e9f;
        }
    }
    __syncthreads();

    {
        int qi = tid >> 4, tx = tid & 15;
        float m = -3.0e38f;
        for (int kk = tx; kk < Sk; kk += 16) m = fmaxf(m, sc[qi][kk]);
        #pragma unroll
        for (int o = 1; o < 16; o <<= 1) m = fmaxf(m, __shfl_xor(m, o));
        float sum = 0.f;
        for (int kk = tx; kk < Sk; kk += 16) {
            float p = __expf(sc[qi][kk] - m);
            sc[qi][kk] = p;
            sum += p;
        }
        #pragma unroll
        for (int o = 1; o < 16; o <<= 1) sum += __shfl_xor(sum, o);
        if (tx == 0) invs[qi] = 1.0f / sum;
    }

    float acc0 = 0.f, acc1 = 0.f, acc2 = 0.f, acc3 = 0.f;
    int d = tid & 63, qg = tid >> 6;
    for (int kk0 = 0; kk0 < Sk; kk0 += 64) {
        __syncthreads();
        #pragma unroll
        for (int c = 0; c < 4; ++c) {
            int ch = c * 256 + tid;
            int r = ch >> 4, dq = (ch & 15) * 4;
            *reinterpret_cast<float4*>(&kv[r][dq]) = *reinterpret_cast<const float4*>(
                &Vp[((size_t)(b * Sk + kk0 + r)) * Dm + hoff + dq]);
        }
        __syncthreads();
        #pragma unroll
        for (int kk = 0; kk < 64; ++kk) {
            float vv = kv[kk][d];
            acc0 += sc[qg * 4 + 0][kk0 + kk] * vv;
            acc1 += sc[qg * 4 + 1][kk0 + kk] * vv;
            acc2 += sc[qg * 4 + 2][kk0 + kk] * vv;
            acc3 += sc[qg * 4 + 3][kk0 + kk] * vv;
        }
    }
    O[((size_t)(b * Sq + q0 + qg * 4 + 0)) * Dm + hoff + d] = acc0 * invs[qg * 4 + 0];
    O[((size_t)(b * Sq + q0 + qg * 4 + 1)) * Dm + hoff + d] = acc1 * invs[qg * 4 + 1];
    O[((size_t)(b * Sq + q0 + qg * 4 + 2)) * Dm + hoff + d] = acc2 * invs[qg * 4 + 2];
    O[((size_t)(b * Sq + q0 + qg * 4 + 3)) * Dm + hoff + d] = acc3 * invs[qg * 4 + 3];
}

// ---------------------------------------------------------------- residual + LN (+ bf16 copy)
__global__ __launch_bounds__(256) void add_ln_k(float* __restrict__ x,
                                                const float* __restrict__ a,
                                                const float* __restrict__ g,
                                                const float* __restrict__ bb,
                                                __bf16* __restrict__ xb)
{
    int row = blockIdx.x;
    size_t base = (size_t)row * Dm;
    int tid = threadIdx.x;
    float v0 = x[base + tid]       + a[base + tid];
    float v1 = x[base + tid + 256] + a[base + tid + 256];
    float s  = v0 + v1;
    float s2 = v0 * v0 + v1 * v1;
    #pragma unroll
    for (int o = 1; o < 64; o <<= 1) {
        s  += __shfl_xor(s, o);
        s2 += __shfl_xor(s2, o);
    }
    __shared__ float red[8];
    int wid = tid >> 6, lane = tid & 63;
    if (lane == 0) { red[wid] = s; red[wid + 4] = s2; }
    __syncthreads();
    s  = red[0] + red[1] + red[2] + red[3];
    s2 = red[4] + red[5] + red[6] + red[7];
    float mean = s * (1.0f / 512.0f);
    float var  = s2 * (1.0f / 512.0f) - mean * mean;
    float rstd = rsqrtf(var + 1e-5f);
    float y0 = (v0 - mean) * rstd * g[tid]       + bb[tid];
    float y1 = (v1 - mean) * rstd * g[tid + 256] + bb[tid + 256];
    x[base + tid]        = y0;
    x[base + tid + 256]  = y1;
    xb[base + tid]       = (__bf16)y0;
    xb[base + tid + 256] = (__bf16)y1;
}

// ---------------------------------------------------------------- launch
extern "C" void kernel_launch(void* const* d_in, const int* in_sizes, int n_in,
                              void* d_out, int out_size, void* d_ws, size_t ws_size,
                              hipStream_t stream)
{
    const int*   src        = (const int*)  d_in[0];
    const int*   tgt        = (const int*)  d_in[1];
    const float* src_emb    = (const float*)d_in[2];
    const float* tgt_emb    = (const float*)d_in[3];
    const float* enc_attn_w = (const float*)d_in[4];
    const float* enc_attn_b = (const float*)d_in[5];
    const float* enc_ffn_w1 = (const float*)d_in[6];
    const float* enc_ffn_b1 = (const float*)d_in[7];
    const float* enc_ffn_w2 = (const float*)d_in[8];
    const float* enc_ffn_b2 = (const float*)d_in[9];
    const float* enc_ln_g   = (const float*)d_in[10];
    const float* enc_ln_b   = (const float*)d_in[11];
    const float* dec_self_w = (const float*)d_in[12];
    const float* dec_self_b = (const float*)d_in[13];
    const float* dec_cross_w= (const float*)d_in[14];
    const float* dec_cross_b= (const float*)d_in[15];
    const float* dec_ffn_w1 = (const float*)d_in[16];
    const float* dec_ffn_b1 = (const float*)d_in[17];
    const float* dec_ffn_w2 = (const float*)d_in[18];
    const float* dec_ffn_b2 = (const float*)d_in[19];
    const float* dec_ln_g   = (const float*)d_in[20];
    const float* dec_ln_b   = (const float*)d_in[21];
    const float* out_w      = (const float*)d_in[22];
    const float* out_b      = (const float*)d_in[23];

    const size_t NROW = (size_t)NTOK * Dm;        // 2,097,152
    const size_t NH1  = (size_t)NTOK * DFFv;      // 8,388,608

    float* ws  = (float*)d_ws;
    float* xe  = ws;            // f32 encoder stream
    float* xd  = xe + NROW;     // f32 decoder stream
    float* qb  = xd + NROW;
    float* kb  = qb + NROW;
    float* vb  = kb + NROW;
    float* ctx = vb + NROW;
    float* t0  = ctx + NROW;

    __bf16* xeb  = (__bf16*)(t0 + NROW);
    __bf16* xdb  = xeb + NROW;
    __bf16* ctxb = xdb + NROW;
    __bf16* h1b  = ctxb + NROW;           // [4096,2048] bf16

    // bf16 transposed weights
    const size_t WSZ  = (size_t)Dm * Dm;          // 262144
    const size_t FSZ  = (size_t)Dm * DFFv;        // 1048576
    __bf16* w_enc_attn = h1b + NH1;               // 24 * WSZ
    __bf16* w_enc_f1   = w_enc_attn + 24 * WSZ;   // 6 * FSZ
    __bf16* w_enc_f2   = w_enc_f1 + 6 * FSZ;
    __bf16* w_dec_self = w_enc_f2 + 6 * FSZ;      // 24 * WSZ
    __bf16* w_dec_cross= w_dec_self + 24 * WSZ;
    __bf16* w_dec_f1   = w_dec_cross + 24 * WSZ;
    __bf16* w_dec_f2   = w_dec_f1 + 6 * FSZ;
    __bf16* w_out      = w_dec_f2 + 6 * FSZ;      // 512*32000

    // ---- weight transpose+convert (per call; graph-capture safe)
    wtr_k<<<dim3(Dm / 32, Dm / 32, 24), 256, 0, stream>>>(enc_attn_w, w_enc_attn, Dm, Dm);
    wtr_k<<<dim3(DFFv / 32, Dm / 32, 6), 256, 0, stream>>>(enc_ffn_w1, w_enc_f1, Dm, DFFv);
    wtr_k<<<dim3(Dm / 32, DFFv / 32, 6), 256, 0, stream>>>(enc_ffn_w2, w_enc_f2, DFFv, Dm);
    wtr_k<<<dim3(Dm / 32, Dm / 32, 24), 256, 0, stream>>>(dec_self_w, w_dec_self, Dm, Dm);
    wtr_k<<<dim3(Dm / 32, Dm / 32, 24), 256, 0, stream>>>(dec_cross_w, w_dec_cross, Dm, Dm);
    wtr_k<<<dim3(DFFv / 32, Dm / 32, 6), 256, 0, stream>>>(dec_ffn_w1, w_dec_f1, Dm, DFFv);
    wtr_k<<<dim3(Dm / 32, DFFv / 32, 6), 256, 0, stream>>>(dec_ffn_w2, w_dec_f2, DFFv, Dm);
    wtr_k<<<dim3(Vv / 32, Dm / 32, 1), 256, 0, stream>>>(out_w, w_out, Dm, Vv);

    auto g64 = [&](const __bf16* A, const __bf16* Wt, const float* bias, float* C, int K) {
        gemm_mfma_k<64, 0, 0><<<dim3(Dm / 64, NTOK / 128), 256, 0, stream>>>(
            A, Wt, bias, C, NTOK, Dm, K);
    };
    auto attn = [&](const float* Q, const float* K, const float* V, float* O,
                    const int* kt, int causal) {
        attn_k<<<dim3(Ss / 16, Hh, Bb), 256, 0, stream>>>(Q, K, V, O, kt, Ss, Ss, causal);
    };
    auto lnorm = [&](float* x, const float* a, const float* g, const float* b, __bf16* xb) {
        add_ln_k<<<NTOK, 256, 0, stream>>>(x, a, g, b, xb);
    };
    auto cvt = [&](const float* in, __bf16* out) {
        cvt_bf16_k<<<(int)(NROW / 8 / 256), 256, 0, stream>>>(in, out, (int)NROW);
    };

    // embeddings + PE
    embed_pe_k<<<NTOK, 256, 0, stream>>>(src, src_emb, xe, xeb, Ss);
    embed_pe_k<<<NTOK, 256, 0, stream>>>(tgt, tgt_emb, xd, xdb, Ss);

    // ---------------- encoder
    for (int i = 0; i < Ll; ++i) {
        const __bf16* W = w_enc_attn + (size_t)i * 4 * WSZ;
        const float* Bv = enc_attn_b + (size_t)i * 4 * Dm;
        g64(xeb, W + 0 * WSZ, Bv + 0 * Dm, qb, Dm);
        g64(xeb, W + 1 * WSZ, Bv + 1 * Dm, kb, Dm);
        g64(xeb, W + 2 * WSZ, Bv + 2 * Dm, vb, Dm);
        attn(qb, kb, vb, ctx, src, 0);
        cvt(ctx, ctxb);
        g64(ctxb, W + 3 * WSZ, Bv + 3 * Dm, t0, Dm);
        lnorm(xe, t0, enc_ln_g + i * 2 * Dm, enc_ln_b + i * 2 * Dm, xeb);
        gemm_mfma_k<128, 1, 1><<<dim3(DFFv / 128, NTOK / 128), 256, 0, stream>>>(
            xeb, w_enc_f1 + (size_t)i * FSZ, enc_ffn_b1 + i * DFFv, h1b, NTOK, DFFv, Dm);
        g64(h1b, w_enc_f2 + (size_t)i * FSZ, enc_ffn_b2 + i * Dm, t0, DFFv);
        lnorm(xe, t0, enc_ln_g + i * 2 * Dm + Dm, enc_ln_b + i * 2 * Dm + Dm, xeb);
    }

    // ---------------- decoder
    for (int i = 0; i < Ll; ++i) {
        const __bf16* Wsf = w_dec_self + (size_t)i * 4 * WSZ;
        const float* Bsf = dec_self_b + (size_t)i * 4 * Dm;
        g64(xdb, Wsf + 0 * WSZ, Bsf + 0 * Dm, qb, Dm);
        g64(xdb, Wsf + 1 * WSZ, Bsf + 1 * Dm, kb, Dm);
        g64(xdb, Wsf + 2 * WSZ, Bsf + 2 * Dm, vb, Dm);
        attn(qb, kb, vb, ctx, tgt, 1);
        cvt(ctx, ctxb);
        g64(ctxb, Wsf + 3 * WSZ, Bsf + 3 * Dm, t0, Dm);
        lnorm(xd, t0, dec_ln_g + i * 3 * Dm, dec_ln_b + i * 3 * Dm, xdb);

        const __bf16* Wc = w_dec_cross + (size_t)i * 4 * WSZ;
        const float* Bc = dec_cross_b + (size_t)i * 4 * Dm;
        g64(xdb, Wc + 0 * WSZ, Bc + 0 * Dm, qb, Dm);
        g64(xeb, Wc + 1 * WSZ, Bc + 1 * Dm, kb, Dm);   // K from encoder memory
        g64(xeb, Wc + 2 * WSZ, Bc + 2 * Dm, vb, Dm);   // V from encoder memory
        attn(qb, kb, vb, ctx, src, 0);
        cvt(ctx, ctxb);
        g64(ctxb, Wc + 3 * WSZ, Bc + 3 * Dm, t0, Dm);
        lnorm(xd, t0, dec_ln_g + i * 3 * Dm + Dm, dec_ln_b + i * 3 * Dm + Dm, xdb);

        gemm_mfma_k<128, 1, 1><<<dim3(DFFv / 128, NTOK / 128), 256, 0, stream>>>(
            xdb, w_dec_f1 + (size_t)i * FSZ, dec_ffn_b1 + i * DFFv, h1b, NTOK, DFFv, Dm);
        g64(h1b, w_dec_f2 + (size_t)i * FSZ, dec_ffn_b2 + i * Dm, t0, DFFv);
        lnorm(xd, t0, dec_ln_g + i * 3 * Dm + 2 * Dm, dec_ln_b + i * 3 * Dm + 2 * Dm, xdb);
    }

    // ---------------- final vocab projection -> d_out [8,512,32000] f32
    gemm_mfma_k<128, 0, 0><<<dim3(Vv / 128, NTOK / 128), 256, 0, stream>>>(
        xdb, w_out, out_b, d_out, NTOK, Vv, Dm);
}

// Round 3
// 2876.169 us; speedup vs baseline: 8.7921x; 4.6148x over previous
//
#include <hip/hip_runtime.h>
#include <hip/hip_bf16.h>

// TransformerNMT r2: bf16 MFMA GEMMs + bf16 MFMA flash attention.
// B=8, S=T=512, D=512, H=8, hd=64, L=6, DFF=2048, V=32000, PAD=0

#define Dm 512
#define Hh 8
#define HD 64
#define Ll 6
#define DFFv 2048
#define Vv 32000
#define Bb 8
#define Ss 512
#define NTOK (Bb * Ss)   // 4096 rows

typedef __bf16 bf16x8 __attribute__((ext_vector_type(8)));
typedef __bf16 bf16x4 __attribute__((ext_vector_type(4)));
typedef float  f32x4  __attribute__((ext_vector_type(4)));

#define GLOAD16(gp, lp) __builtin_amdgcn_global_load_lds( \
    (const __attribute__((address_space(1))) unsigned int*)(const void*)(gp), \
    (__attribute__((address_space(3))) unsigned int*)(void*)(lp), 16, 0, 0)

// ---------------------------------------------------------------- embed + PE (f32 + bf16 out)
__global__ void embed_pe_k(const int* __restrict__ tok, const float* __restrict__ emb,
                           float* __restrict__ out, __bf16* __restrict__ outb, int Slen)
{
    int row = blockIdx.x;
    int s = row % Slen;
    int t = tok[row];
    const float* e = emb + (size_t)t * Dm;
    float* o = out + (size_t)row * Dm;
    __bf16* ob = outb + (size_t)row * Dm;
    for (int dd = threadIdx.x; dd < Dm; dd += blockDim.x) {
        int j = dd >> 1;
        float div = expf((float)(2 * j) * (-9.210340371976184f / 512.0f));
        float ang = (float)s * div;
        float pe = (dd & 1) ? cosf(ang) : sinf(ang);
        float v = e[dd] * 22.627416997969522f + pe;   // sqrt(512)
        o[dd] = v;
        ob[dd] = (__bf16)v;
    }
}

// ---------------------------------------------------------------- weight transpose+convert
// W [K,N] f32 -> Wt [N,K] bf16, per matrix (blockIdx.z)
__global__ __launch_bounds__(256) void wtr_k(const float* __restrict__ W,
                                             __bf16* __restrict__ Wt, int K, int N)
{
    __shared__ float t[32][33];
    size_t msz = (size_t)K * N;
    const float* Wm = W + (size_t)blockIdx.z * msz;
    __bf16* Wtm = Wt + (size_t)blockIdx.z * msz;
    int n0 = blockIdx.x * 32, k0 = blockIdx.y * 32;
    int r = threadIdx.x >> 3, c4 = (threadIdx.x & 7) * 4;
    float4 v = *reinterpret_cast<const float4*>(&Wm[(size_t)(k0 + r) * N + n0 + c4]);
    t[r][c4] = v.x; t[r][c4 + 1] = v.y; t[r][c4 + 2] = v.z; t[r][c4 + 3] = v.w;
    __syncthreads();
    int n = threadIdx.x >> 3, kq = (threadIdx.x & 7) * 4;
    bf16x4 o;
    o[0] = (__bf16)t[kq + 0][n]; o[1] = (__bf16)t[kq + 1][n];
    o[2] = (__bf16)t[kq + 2][n]; o[3] = (__bf16)t[kq + 3][n];
    *reinterpret_cast<bf16x4*>(&Wtm[(size_t)(n0 + n) * K + k0 + kq]) = o;
}

// ---------------------------------------------------------------- V transpose
// vbb [B*512 tok][512 feat] bf16 -> vbT [(b*8+h)*64 + f][512 key] bf16
__global__ __launch_bounds__(256) void vtr_k(const __bf16* __restrict__ vbb,
                                             __bf16* __restrict__ vbT)
{
    __shared__ __bf16 t[64][72];   // 144B pitch: 16B aligned rows
    int h = blockIdx.x, b = blockIdx.y;
    for (int s0 = 0; s0 < 512; s0 += 64) {
        __syncthreads();
        #pragma unroll
        for (int c = 0; c < 2; ++c) {
            int ch = c * 256 + threadIdx.x;   // 0..511
            int s = ch >> 3, f8 = (ch & 7) * 8;
            bf16x8 v = *reinterpret_cast<const bf16x8*>(
                &vbb[(size_t)(b * 512 + s0 + s) * 512 + h * 64 + f8]);
            #pragma unroll
            for (int e = 0; e < 8; ++e) t[f8 + e][s] = v[e];
        }
        __syncthreads();
        #pragma unroll
        for (int c = 0; c < 2; ++c) {
            int ch = c * 256 + threadIdx.x;
            int f = ch >> 3, k8 = (ch & 7) * 8;
            bf16x8 v;
            #pragma unroll
            for (int e = 0; e < 8; ++e) v[e] = t[f][k8 + e];
            *reinterpret_cast<bf16x8*>(
                &vbT[(size_t)((b * 8 + h) * 64 + f) * 512 + s0 + k8]) = v;
        }
    }
}

// ---------------------------------------------------------------- MFMA GEMM
// C[M,N] = A[M,K](bf16) @ Wt[N,K](bf16)^T + bias, opt ReLU, out f32 or bf16.
template<int BN, int RELU, int OUTBF16>
__global__ __launch_bounds__(256) void gemm_mfma_k(const __bf16* __restrict__ A,
                                                   const __bf16* __restrict__ Wt,
                                                   const float* __restrict__ bias,
                                                   void* __restrict__ Cout,
                                                   int M, int N, int K)
{
    constexpr int NF_N = BN / 32;
    constexpr int WCS  = BN / 2;
    __shared__ __bf16 As[128 * 32];
    __shared__ __bf16 Bs[BN * 32];
    const int tid = threadIdx.x;
    const int wave = tid >> 6, lane = tid & 63;
    const int wr = wave >> 1, wc = wave & 1;
    const int row0 = blockIdx.y * 128, col0 = blockIdx.x * BN;

    f32x4 acc[4][NF_N] = {};

    const int rsub = lane >> 2;
    const int kel  = (lane & 3) * 8;
    const int fr   = lane & 15;
    const int kg   = lane >> 4;

    for (int k0 = 0; k0 < K; k0 += 32) {
        #pragma unroll
        for (int cc = 0; cc < 2; ++cc) {
            int c = wave * 2 + cc;
            int row = c * 16 + rsub;
            GLOAD16(A + (size_t)(row0 + row) * K + k0 + kel,
                    As + c * 512 + lane * 8);
        }
        if constexpr (BN == 128) {
            #pragma unroll
            for (int cc = 0; cc < 2; ++cc) {
                int c = wave * 2 + cc;
                int row = c * 16 + rsub;
                GLOAD16(Wt + (size_t)(col0 + row) * K + k0 + kel,
                        Bs + c * 512 + lane * 8);
            }
        } else {
            int c = wave;
            int row = c * 16 + rsub;
            GLOAD16(Wt + (size_t)(col0 + row) * K + k0 + kel,
                    Bs + c * 512 + lane * 8);
        }
        __syncthreads();

        const bf16x8* Av = reinterpret_cast<const bf16x8*>(As);
        const bf16x8* Bv = reinterpret_cast<const bf16x8*>(Bs);
        bf16x8 af[4], bq[NF_N];
        #pragma unroll
        for (int m = 0; m < 4; ++m)
            af[m] = Av[(wr * 64 + m * 16 + fr) * 4 + kg];
        #pragma unroll
        for (int n = 0; n < NF_N; ++n)
            bq[n] = Bv[(wc * WCS + n * 16 + fr) * 4 + kg];
        #pragma unroll
        for (int m = 0; m < 4; ++m)
            #pragma unroll
            for (int n = 0; n < NF_N; ++n)
                acc[m][n] = __builtin_amdgcn_mfma_f32_16x16x32_bf16(
                    af[m], bq[n], acc[m][n], 0, 0, 0);
        __syncthreads();
    }

    #pragma unroll
    for (int m = 0; m < 4; ++m) {
        #pragma unroll
        for (int n = 0; n < NF_N; ++n) {
            int col = col0 + wc * WCS + n * 16 + fr;
            float bv = bias[col];
            #pragma unroll
            for (int j = 0; j < 4; ++j) {
                int row = row0 + wr * 64 + m * 16 + kg * 4 + j;
                float v = acc[m][n][j] + bv;
                if (RELU) v = fmaxf(v, 0.f);
                if (OUTBF16)
                    ((__bf16*)Cout)[(size_t)row * N + col] = (__bf16)v;
                else
                    ((float*)Cout)[(size_t)row * N + col] = v;
            }
        }
    }
}

// ---------------------------------------------------------------- MFMA flash attention
// Qb,Kb: [4096][512] bf16 row-major; VbT: [(b*8+h)*64+f][512] bf16; Ob: [4096][512] bf16.
// Block: 256 thr = 4 waves; wave w owns q-rows q0+w*16..+15. KVBLK=64. Swapped QK^T.
__global__ __launch_bounds__(256) void attn_mfma_k(const __bf16* __restrict__ Qb,
                                                   const __bf16* __restrict__ Kb,
                                                   const __bf16* __restrict__ VbT,
                                                   __bf16* __restrict__ Ob,
                                                   const int* __restrict__ key_tok,
                                                   int causal)
{
    __shared__ __bf16 Ks[64 * 64];     // [key][feat], XOR-swizzled content
    __shared__ __bf16 Vs[64 * 64];     // [feat][key], XOR-swizzled content
    __shared__ __bf16 Pl[4][16 * 64];  // per-wave P, XOR-swizzled

    const int tid = threadIdx.x;
    const int w = tid >> 6, lane = tid & 63;
    const int fr = lane & 15, kg = lane >> 4;
    const int q0 = blockIdx.x * 64;
    const int h = blockIdx.y, b = blockIdx.z;
    const int qrow = q0 + w * 16 + fr;        // this lane's q (S^T domain)
    const int swz = (fr & 7) << 4;

    // Q as B-operand: lane holds Q[qrow][ks*32 + kg*8 + e]
    bf16x8 qf[2];
    {
        const __bf16* qp = Qb + ((size_t)(b * 512 + qrow) * 512 + h * 64 + kg * 8);
        qf[0] = *reinterpret_cast<const bf16x8*>(qp);
        qf[1] = *reinterpret_cast<const bf16x8*>(qp + 32);
    }

    f32x4 po[4] = {};                 // O acc: po[nf][j], q_o = kg*4+j, feat = nf*16+fr
    float m_run = -3.0e38f, l_run = 0.f;
    __bf16* pw = Pl[w];

    const int kend = causal ? (q0 + 64) : 512;
    for (int kk0 = 0; kk0 < kend; kk0 += 64) {
        // ---- stage K-tile [64 key][64 feat] and V-tile [64 feat][64 key] (swizzled src)
        #pragma unroll
        for (int c = 0; c < 2; ++c) {
            int ch = c * 256 + tid;           // 0..511
            int r = ch >> 3, gs = (ch & 7) ^ (r & 7);
            GLOAD16(Kb + ((size_t)(b * 512 + kk0 + r) * 512 + h * 64 + gs * 8),
                    Ks + ch * 8);
            GLOAD16(VbT + ((size_t)((b * 8 + h) * 64 + r) * 512 + kk0 + gs * 8),
                    Vs + ch * 8);
        }
        __syncthreads();

        // ---- key pad-mask bitmap for this tile
        unsigned long long vm = __ballot(key_tok[b * 512 + kk0 + lane] != 0);

        // ---- S^T = K @ Q^T : st[kt][j] = S[key=kk0+kt*16+kg*4+j][q=qrow]
        f32x4 st[4];
        #pragma unroll
        for (int kt = 0; kt < 4; ++kt) {
            f32x4 s = {};
            #pragma unroll
            for (int ks = 0; ks < 2; ++ks) {
                int byte = ((kt * 16 + fr) * 128 + ks * 64 + kg * 16) ^ swz;
                bf16x8 kf = *reinterpret_cast<const bf16x8*>((const char*)Ks + byte);
                s = __builtin_amdgcn_mfma_f32_16x16x32_bf16(kf, qf[ks], s, 0, 0, 0);
            }
            st[kt] = s;
        }

        // ---- mask + online softmax (row q = fr, spread over 4 kg-lanes)
        float sv[4][4];
        float mloc = -3.0e38f;
        #pragma unroll
        for (int kt = 0; kt < 4; ++kt)
            #pragma unroll
            for (int j = 0; j < 4; ++j) {
                int kl = kt * 16 + kg * 4 + j;
                float s = st[kt][j] * 0.125f;
                bool ok = (vm >> kl) & 1ull;
                if (causal && (kk0 + kl > qrow)) ok = false;
                s = ok ? s : -1e9f;
                sv[kt][j] = s;
                mloc = fmaxf(mloc, s);
            }
        mloc = fmaxf(mloc, __shfl_xor(mloc, 16));
        mloc = fmaxf(mloc, __shfl_xor(mloc, 32));
        float m_new = fmaxf(m_run, mloc);
        float scale = __expf(m_run - m_new);
        float ls = 0.f;
        #pragma unroll
        for (int kt = 0; kt < 4; ++kt)
            #pragma unroll
            for (int j = 0; j < 4; ++j) {
                float p = __expf(sv[kt][j] - m_new);
                sv[kt][j] = p;
                ls += p;
            }
        ls += __shfl_xor(ls, 16);
        ls += __shfl_xor(ls, 32);
        l_run = l_run * scale + ls;
        m_run = m_new;

        // ---- P -> per-wave LDS (bf16, swizzled rows of 128B)
        #pragma unroll
        for (int kt = 0; kt < 4; ++kt)
            #pragma unroll
            for (int c = 0; c < 2; ++c) {
                union { __bf16 hh[2]; unsigned u; } pk;
                pk.hh[0] = (__bf16)sv[kt][2 * c];
                pk.hh[1] = (__bf16)sv[kt][2 * c + 1];
                int byte = (fr * 128 + kt * 32 + kg * 8 + c * 4) ^ swz;
                *reinterpret_cast<unsigned*>((char*)pw + byte) = pk.u;
            }

        // ---- rescale O (O domain: q_o = kg*4 + j; scale held by lane q_o)
        {
            int qb4 = kg * 4;
            float s0 = __shfl(scale, qb4 + 0), s1 = __shfl(scale, qb4 + 1);
            float s2 = __shfl(scale, qb4 + 2), s3 = __shfl(scale, qb4 + 3);
            #pragma unroll
            for (int nf = 0; nf < 4; ++nf) {
                po[nf][0] *= s0; po[nf][1] *= s1;
                po[nf][2] *= s2; po[nf][3] *= s3;
            }
        }

        // ---- PV: O += P @ V
        #pragma unroll
        for (int ks2 = 0; ks2 < 2; ++ks2) {
            int pbyte = (fr * 128 + ks2 * 64 + kg * 16) ^ swz;
            bf16x8 pa = *reinterpret_cast<const bf16x8*>((const char*)pw + pbyte);
            #pragma unroll
            for (int nf = 0; nf < 4; ++nf) {
                int vbyte = ((nf * 16 + fr) * 128 + ks2 * 64 + kg * 16) ^ swz;
                bf16x8 vf = *reinterpret_cast<const bf16x8*>((const char*)Vs + vbyte);
                po[nf] = __builtin_amdgcn_mfma_f32_16x16x32_bf16(pa, vf, po[nf], 0, 0, 0);
            }
        }
        __syncthreads();
    }

    // ---- epilogue: divide by l, store bf16
    {
        int qb4 = kg * 4;
        float r0 = 1.0f / __shfl(l_run, qb4 + 0);
        float r1 = 1.0f / __shfl(l_run, qb4 + 1);
        float r2 = 1.0f / __shfl(l_run, qb4 + 2);
        float r3 = 1.0f / __shfl(l_run, qb4 + 3);
        #pragma unroll
        for (int nf = 0; nf < 4; ++nf) {
            size_t base = (size_t)(b * 512 + q0 + w * 16 + qb4) * 512 + h * 64 + nf * 16 + fr;
            Ob[base]           = (__bf16)(po[nf][0] * r0);
            Ob[base + 512]     = (__bf16)(po[nf][1] * r1);
            Ob[base + 1024]    = (__bf16)(po[nf][2] * r2);
            Ob[base + 1536]    = (__bf16)(po[nf][3] * r3);
        }
    }
}

// ---------------------------------------------------------------- residual + LN (+ bf16 copy)
__global__ __launch_bounds__(256) void add_ln_k(float* __restrict__ x,
                                                const float* __restrict__ a,
                                                const float* __restrict__ g,
                                                const float* __restrict__ bb,
                                                __bf16* __restrict__ xb)
{
    int row = blockIdx.x;
    size_t base = (size_t)row * Dm;
    int tid = threadIdx.x;
    float v0 = x[base + tid]       + a[base + tid];
    float v1 = x[base + tid + 256] + a[base + tid + 256];
    float s  = v0 + v1;
    float s2 = v0 * v0 + v1 * v1;
    #pragma unroll
    for (int o = 1; o < 64; o <<= 1) {
        s  += __shfl_xor(s, o);
        s2 += __shfl_xor(s2, o);
    }
    __shared__ float red[8];
    int wid = tid >> 6, lane = tid & 63;
    if (lane == 0) { red[wid] = s; red[wid + 4] = s2; }
    __syncthreads();
    s  = red[0] + red[1] + red[2] + red[3];
    s2 = red[4] + red[5] + red[6] + red[7];
    float mean = s * (1.0f / 512.0f);
    float var  = s2 * (1.0f / 512.0f) - mean * mean;
    float rstd = rsqrtf(var + 1e-5f);
    float y0 = (v0 - mean) * rstd * g[tid]       + bb[tid];
    float y1 = (v1 - mean) * rstd * g[tid + 256] + bb[tid + 256];
    x[base + tid]        = y0;
    x[base + tid + 256]  = y1;
    xb[base + tid]       = (__bf16)y0;
    xb[base + tid + 256] = (__bf16)y1;
}

// ---------------------------------------------------------------- launch
extern "C" void kernel_launch(void* const* d_in, const int* in_sizes, int n_in,
                              void* d_out, int out_size, void* d_ws, size_t ws_size,
                              hipStream_t stream)
{
    const int*   src        = (const int*)  d_in[0];
    const int*   tgt        = (const int*)  d_in[1];
    const float* src_emb    = (const float*)d_in[2];
    const float* tgt_emb    = (const float*)d_in[3];
    const float* enc_attn_w = (const float*)d_in[4];
    const float* enc_attn_b = (const float*)d_in[5];
    const float* enc_ffn_w1 = (const float*)d_in[6];
    const float* enc_ffn_b1 = (const float*)d_in[7];
    const float* enc_ffn_w2 = (const float*)d_in[8];
    const float* enc_ffn_b2 = (const float*)d_in[9];
    const float* enc_ln_g   = (const float*)d_in[10];
    const float* enc_ln_b   = (const float*)d_in[11];
    const float* dec_self_w = (const float*)d_in[12];
    const float* dec_self_b = (const float*)d_in[13];
    const float* dec_cross_w= (const float*)d_in[14];
    const float* dec_cross_b= (const float*)d_in[15];
    const float* dec_ffn_w1 = (const float*)d_in[16];
    const float* dec_ffn_b1 = (const float*)d_in[17];
    const float* dec_ffn_w2 = (const float*)d_in[18];
    const float* dec_ffn_b2 = (const float*)d_in[19];
    const float* dec_ln_g   = (const float*)d_in[20];
    const float* dec_ln_b   = (const float*)d_in[21];
    const float* out_w      = (const float*)d_in[22];
    const float* out_b      = (const float*)d_in[23];

    const size_t NROW = (size_t)NTOK * Dm;        // 2,097,152
    const size_t NH1  = (size_t)NTOK * DFFv;      // 8,388,608

    float* ws  = (float*)d_ws;
    float* xe  = ws;            // f32 encoder stream
    float* xd  = xe + NROW;     // f32 decoder stream
    float* t0  = xd + NROW;     // f32 sublayer output (pre-LN)

    __bf16* xeb  = (__bf16*)(t0 + NROW);
    __bf16* xdb  = xeb + NROW;
    __bf16* qbb  = xdb + NROW;
    __bf16* kbb  = qbb + NROW;
    __bf16* vbb  = kbb + NROW;
    __bf16* vbT  = vbb + NROW;            // [(b*8+h)*64+f][512]
    __bf16* ctxb = vbT + NROW;
    __bf16* h1b  = ctxb + NROW;           // [4096,2048] bf16

    const size_t WSZ  = (size_t)Dm * Dm;          // 262144
    const size_t FSZ  = (size_t)Dm * DFFv;        // 1048576
    __bf16* w_enc_attn = h1b + NH1;
    __bf16* w_enc_f1   = w_enc_attn + 24 * WSZ;
    __bf16* w_enc_f2   = w_enc_f1 + 6 * FSZ;
    __bf16* w_dec_self = w_enc_f2 + 6 * FSZ;
    __bf16* w_dec_cross= w_dec_self + 24 * WSZ;
    __bf16* w_dec_f1   = w_dec_cross + 24 * WSZ;
    __bf16* w_dec_f2   = w_dec_f1 + 6 * FSZ;
    __bf16* w_out      = w_dec_f2 + 6 * FSZ;      // 512*32000

    // ---- weight transpose+convert
    wtr_k<<<dim3(Dm / 32, Dm / 32, 24), 256, 0, stream>>>(enc_attn_w, w_enc_attn, Dm, Dm);
    wtr_k<<<dim3(DFFv / 32, Dm / 32, 6), 256, 0, stream>>>(enc_ffn_w1, w_enc_f1, Dm, DFFv);
    wtr_k<<<dim3(Dm / 32, DFFv / 32, 6), 256, 0, stream>>>(enc_ffn_w2, w_enc_f2, DFFv, Dm);
    wtr_k<<<dim3(Dm / 32, Dm / 32, 24), 256, 0, stream>>>(dec_self_w, w_dec_self, Dm, Dm);
    wtr_k<<<dim3(Dm / 32, Dm / 32, 24), 256, 0, stream>>>(dec_cross_w, w_dec_cross, Dm, Dm);
    wtr_k<<<dim3(DFFv / 32, Dm / 32, 6), 256, 0, stream>>>(dec_ffn_w1, w_dec_f1, Dm, DFFv);
    wtr_k<<<dim3(Dm / 32, DFFv / 32, 6), 256, 0, stream>>>(dec_ffn_w2, w_dec_f2, DFFv, Dm);
    wtr_k<<<dim3(Vv / 32, Dm / 32, 1), 256, 0, stream>>>(out_w, w_out, Dm, Vv);

    auto g64f = [&](const __bf16* A, const __bf16* Wt, const float* bias, float* C, int K) {
        gemm_mfma_k<64, 0, 0><<<dim3(Dm / 64, NTOK / 128), 256, 0, stream>>>(
            A, Wt, bias, C, NTOK, Dm, K);
    };
    auto g64b = [&](const __bf16* A, const __bf16* Wt, const float* bias, __bf16* C, int K) {
        gemm_mfma_k<64, 0, 1><<<dim3(Dm / 64, NTOK / 128), 256, 0, stream>>>(
            A, Wt, bias, C, NTOK, Dm, K);
    };
    auto attn = [&](const __bf16* Q, const __bf16* K, const __bf16* Vt, __bf16* O,
                    const int* kt, int causal) {
        attn_mfma_k<<<dim3(Ss / 64, Hh, Bb), 256, 0, stream>>>(Q, K, Vt, O, kt, causal);
    };
    auto lnorm = [&](float* x, const float* a, const float* g, const float* b, __bf16* xb) {
        add_ln_k<<<NTOK, 256, 0, stream>>>(x, a, g, b, xb);
    };
    auto vtr = [&]() { vtr_k<<<dim3(Hh, Bb), 256, 0, stream>>>(vbb, vbT); };

    // embeddings + PE
    embed_pe_k<<<NTOK, 256, 0, stream>>>(src, src_emb, xe, xeb, Ss);
    embed_pe_k<<<NTOK, 256, 0, stream>>>(tgt, tgt_emb, xd, xdb, Ss);

    // ---------------- encoder
    for (int i = 0; i < Ll; ++i) {
        const __bf16* W = w_enc_attn + (size_t)i * 4 * WSZ;
        const float* Bv = enc_attn_b + (size_t)i * 4 * Dm;
        g64b(xeb, W + 0 * WSZ, Bv + 0 * Dm, qbb, Dm);
        g64b(xeb, W + 1 * WSZ, Bv + 1 * Dm, kbb, Dm);
        g64b(xeb, W + 2 * WSZ, Bv + 2 * Dm, vbb, Dm);
        vtr();
        attn(qbb, kbb, vbT, ctxb, src, 0);
        g64f(ctxb, W + 3 * WSZ, Bv + 3 * Dm, t0, Dm);
        lnorm(xe, t0, enc_ln_g + i * 2 * Dm, enc_ln_b + i * 2 * Dm, xeb);
        gemm_mfma_k<128, 1, 1><<<dim3(DFFv / 128, NTOK / 128), 256, 0, stream>>>(
            xeb, w_enc_f1 + (size_t)i * FSZ, enc_ffn_b1 + i * DFFv, h1b, NTOK, DFFv, Dm);
        g64f(h1b, w_enc_f2 + (size_t)i * FSZ, enc_ffn_b2 + i * Dm, t0, DFFv);
        lnorm(xe, t0, enc_ln_g + i * 2 * Dm + Dm, enc_ln_b + i * 2 * Dm + Dm, xeb);
    }

    // ---------------- decoder
    for (int i = 0; i < Ll; ++i) {
        const __bf16* Wsf = w_dec_self + (size_t)i * 4 * WSZ;
        const float* Bsf = dec_self_b + (size_t)i * 4 * Dm;
        g64b(xdb, Wsf + 0 * WSZ, Bsf + 0 * Dm, qbb, Dm);
        g64b(xdb, Wsf + 1 * WSZ, Bsf + 1 * Dm, kbb, Dm);
        g64b(xdb, Wsf + 2 * WSZ, Bsf + 2 * Dm, vbb, Dm);
        vtr();
        attn(qbb, kbb, vbT, ctxb, tgt, 1);                   // causal + tgt pad
        g64f(ctxb, Wsf + 3 * WSZ, Bsf + 3 * Dm, t0, Dm);
        lnorm(xd, t0, dec_ln_g + i * 3 * Dm, dec_ln_b + i * 3 * Dm, xdb);

        const __bf16* Wc = w_dec_cross + (size_t)i * 4 * WSZ;
        const float* Bc = dec_cross_b + (size_t)i * 4 * Dm;
        g64b(xdb, Wc + 0 * WSZ, Bc + 0 * Dm, qbb, Dm);
        g64b(xeb, Wc + 1 * WSZ, Bc + 1 * Dm, kbb, Dm);   // K from encoder memory
        g64b(xeb, Wc + 2 * WSZ, Bc + 2 * Dm, vbb, Dm);   // V from encoder memory
        vtr();
        attn(qbb, kbb, vbT, ctxb, src, 0);                   // src pad
        g64f(ctxb, Wc + 3 * WSZ, Bc + 3 * Dm, t0, Dm);
        lnorm(xd, t0, dec_ln_g + i * 3 * Dm + Dm, dec_ln_b + i * 3 * Dm + Dm, xdb);

        gemm_mfma_k<128, 1, 1><<<dim3(DFFv / 128, NTOK / 128), 256, 0, stream>>>(
            xdb, w_dec_f1 + (size_t)i * FSZ, dec_ffn_b1 + i * DFFv, h1b, NTOK, DFFv, Dm);
        g64f(h1b, w_dec_f2 + (size_t)i * FSZ, dec_ffn_b2 + i * Dm, t0, DFFv);
        lnorm(xd, t0, dec_ln_g + i * 3 * Dm + 2 * Dm, dec_ln_b + i * 3 * Dm + 2 * Dm, xdb);
    }

    // ---------------- final vocab projection -> d_out [8,512,32000] f32
    gemm_mfma_k<128, 0, 0><<<dim3(Vv / 128, NTOK / 128), 256, 0, stream>>>(
        xdb, w_out, out_b, d_out, NTOK, Vv, Dm);
}

// Round 4
// 2550.090 us; speedup vs baseline: 9.9164x; 1.1279x over previous
//
#include <hip/hip_runtime.h>
#include <hip/hip_bf16.h>

// TransformerNMT r3: fused QKV / cross-KV projections with V-transpose folded
// into the GEMM epilogue. bf16 MFMA GEMMs + bf16 MFMA flash attention.
// B=8, S=T=512, D=512, H=8, hd=64, L=6, DFF=2048, V=32000, PAD=0

#define Dm 512
#define Hh 8
#define HD 64
#define Ll 6
#define DFFv 2048
#define Vv 32000
#define Bb 8
#define Ss 512
#define NTOK (Bb * Ss)   // 4096 rows

typedef __bf16 bf16x8 __attribute__((ext_vector_type(8)));
typedef __bf16 bf16x4 __attribute__((ext_vector_type(4)));
typedef float  f32x4  __attribute__((ext_vector_type(4)));

#define GLOAD16(gp, lp) __builtin_amdgcn_global_load_lds( \
    (const __attribute__((address_space(1))) unsigned int*)(const void*)(gp), \
    (__attribute__((address_space(3))) unsigned int*)(void*)(lp), 16, 0, 0)

// ---------------------------------------------------------------- embed + PE (f32 + bf16 out)
__global__ void embed_pe_k(const int* __restrict__ tok, const float* __restrict__ emb,
                           float* __restrict__ out, __bf16* __restrict__ outb, int Slen)
{
    int row = blockIdx.x;
    int s = row % Slen;
    int t = tok[row];
    const float* e = emb + (size_t)t * Dm;
    float* o = out + (size_t)row * Dm;
    __bf16* ob = outb + (size_t)row * Dm;
    for (int dd = threadIdx.x; dd < Dm; dd += blockDim.x) {
        int j = dd >> 1;
        float div = expf((float)(2 * j) * (-9.210340371976184f / 512.0f));
        float ang = (float)s * div;
        float pe = (dd & 1) ? cosf(ang) : sinf(ang);
        float v = e[dd] * 22.627416997969522f + pe;   // sqrt(512)
        o[dd] = v;
        ob[dd] = (__bf16)v;
    }
}

// ---------------------------------------------------------------- weight transpose+convert
// W [K,N] f32 -> Wt [N,K] bf16, per matrix (blockIdx.z)
__global__ __launch_bounds__(256) void wtr_k(const float* __restrict__ W,
                                             __bf16* __restrict__ Wt, int K, int N)
{
    __shared__ float t[32][33];
    size_t msz = (size_t)K * N;
    const float* Wm = W + (size_t)blockIdx.z * msz;
    __bf16* Wtm = Wt + (size_t)blockIdx.z * msz;
    int n0 = blockIdx.x * 32, k0 = blockIdx.y * 32;
    int r = threadIdx.x >> 3, c4 = (threadIdx.x & 7) * 4;
    float4 v = *reinterpret_cast<const float4*>(&Wm[(size_t)(k0 + r) * N + n0 + c4]);
    t[r][c4] = v.x; t[r][c4 + 1] = v.y; t[r][c4 + 2] = v.z; t[r][c4 + 3] = v.w;
    __syncthreads();
    int n = threadIdx.x >> 3, kq = (threadIdx.x & 7) * 4;
    bf16x4 o;
    o[0] = (__bf16)t[kq + 0][n]; o[1] = (__bf16)t[kq + 1][n];
    o[2] = (__bf16)t[kq + 2][n]; o[3] = (__bf16)t[kq + 3][n];
    *reinterpret_cast<bf16x4*>(&Wtm[(size_t)(n0 + n) * K + k0 + kq]) = o;
}

// ---------------------------------------------------------------- MFMA GEMM
// C[M,N] = A[M,K](bf16) @ Wt[N,K](bf16)^T + bias.
// MODE 0: f32 out [M,N]
// MODE 1: bf16 out [M,N] (+optional RELU)
// MODE 2: N=1536 fused QKV -> seg0 Cq[row*512+c], seg1 Ck, seg2 V transposed to vT
// MODE 3: N=1024 fused KV  -> seg0 Ck, seg1 V transposed to vT
// vT layout: [((b*8+h)*64 + f)*512 + s], b=row>>9, s=row&511, h=c>>6, f=c&63.
template<int BN, int RELU, int MODE>
__global__ __launch_bounds__(256) void gemm_mfma_k(const __bf16* __restrict__ A,
                                                   const __bf16* __restrict__ Wt,
                                                   const float* __restrict__ bias,
                                                   void* __restrict__ Cout,
                                                   __bf16* __restrict__ out_k,
                                                   __bf16* __restrict__ out_vT,
                                                   int M, int N, int K)
{
    constexpr int NF_N = BN / 32;
    constexpr int WCS  = BN / 2;
    __shared__ __bf16 As[128 * 32];
    __shared__ __bf16 Bs[BN * 32];
    const int tid = threadIdx.x;
    const int wave = tid >> 6, lane = tid & 63;
    const int wr = wave >> 1, wc = wave & 1;
    const int row0 = blockIdx.y * 128, col0 = blockIdx.x * BN;

    f32x4 acc[4][NF_N] = {};

    const int rsub = lane >> 2;
    const int kel  = (lane & 3) * 8;
    const int fr   = lane & 15;
    const int kg   = lane >> 4;

    for (int k0 = 0; k0 < K; k0 += 32) {
        #pragma unroll
        for (int cc = 0; cc < 2; ++cc) {
            int c = wave * 2 + cc;
            int row = c * 16 + rsub;
            GLOAD16(A + (size_t)(row0 + row) * K + k0 + kel,
                    As + c * 512 + lane * 8);
        }
        if constexpr (BN == 128) {
            #pragma unroll
            for (int cc = 0; cc < 2; ++cc) {
                int c = wave * 2 + cc;
                int row = c * 16 + rsub;
                GLOAD16(Wt + (size_t)(col0 + row) * K + k0 + kel,
                        Bs + c * 512 + lane * 8);
            }
        } else {
            int c = wave;
            int row = c * 16 + rsub;
            GLOAD16(Wt + (size_t)(col0 + row) * K + k0 + kel,
                    Bs + c * 512 + lane * 8);
        }
        __syncthreads();

        const bf16x8* Av = reinterpret_cast<const bf16x8*>(As);
        const bf16x8* Bv = reinterpret_cast<const bf16x8*>(Bs);
        bf16x8 af[4], bq[NF_N];
        #pragma unroll
        for (int m = 0; m < 4; ++m)
            af[m] = Av[(wr * 64 + m * 16 + fr) * 4 + kg];
        #pragma unroll
        for (int n = 0; n < NF_N; ++n)
            bq[n] = Bv[(wc * WCS + n * 16 + fr) * 4 + kg];
        #pragma unroll
        for (int m = 0; m < 4; ++m)
            #pragma unroll
            for (int n = 0; n < NF_N; ++n)
                acc[m][n] = __builtin_amdgcn_mfma_f32_16x16x32_bf16(
                    af[m], bq[n], acc[m][n], 0, 0, 0);
        __syncthreads();
    }

    #pragma unroll
    for (int m = 0; m < 4; ++m) {
        #pragma unroll
        for (int n = 0; n < NF_N; ++n) {
            int colg = col0 + wc * WCS + n * 16 + fr;
            float bv = bias[colg];
            #pragma unroll
            for (int j = 0; j < 4; ++j) {
                int row = row0 + wr * 64 + m * 16 + kg * 4 + j;
                float v = acc[m][n][j] + bv;
                if (RELU) v = fmaxf(v, 0.f);
                if constexpr (MODE == 0) {
                    ((float*)Cout)[(size_t)row * N + colg] = v;
                } else if constexpr (MODE == 1) {
                    ((__bf16*)Cout)[(size_t)row * N + colg] = (__bf16)v;
                } else {
                    int seg = colg >> 9;          // uniform per block (512%BN==0)
                    int c = colg & 511;
                    bool isV = (MODE == 2) ? (seg == 2) : (seg == 1);
                    if (!isV) {
                        __bf16* o = (MODE == 2 && seg == 1) ? out_k : (__bf16*)Cout;
                        o[(size_t)row * 512 + c] = (__bf16)v;
                    } else {
                        int bi = row >> 9, s = row & 511;
                        int hh = c >> 6, f = c & 63;
                        out_vT[(size_t)((bi * 8 + hh) * 64 + f) * 512 + s] = (__bf16)v;
                    }
                }
            }
        }
    }
}

// ---------------------------------------------------------------- MFMA flash attention
// Qb,Kb: [4096][512] bf16 row-major; VbT: [(b*8+h)*64+f][512] bf16; Ob: [4096][512] bf16.
__global__ __launch_bounds__(256) void attn_mfma_k(const __bf16* __restrict__ Qb,
                                                   const __bf16* __restrict__ Kb,
                                                   const __bf16* __restrict__ VbT,
                                                   __bf16* __restrict__ Ob,
                                                   const int* __restrict__ key_tok,
                                                   int causal)
{
    __shared__ __bf16 Ks[64 * 64];     // [key][feat], XOR-swizzled content
    __shared__ __bf16 Vs[64 * 64];     // [feat][key], XOR-swizzled content
    __shared__ __bf16 Pl[4][16 * 64];  // per-wave P, XOR-swizzled

    const int tid = threadIdx.x;
    const int w = tid >> 6, lane = tid & 63;
    const int fr = lane & 15, kg = lane >> 4;
    const int q0 = blockIdx.x * 64;
    const int h = blockIdx.y, b = blockIdx.z;
    const int qrow = q0 + w * 16 + fr;
    const int swz = (fr & 7) << 4;

    bf16x8 qf[2];
    {
        const __bf16* qp = Qb + ((size_t)(b * 512 + qrow) * 512 + h * 64 + kg * 8);
        qf[0] = *reinterpret_cast<const bf16x8*>(qp);
        qf[1] = *reinterpret_cast<const bf16x8*>(qp + 32);
    }

    f32x4 po[4] = {};
    float m_run = -3.0e38f, l_run = 0.f;
    __bf16* pw = Pl[w];

    const int kend = causal ? (q0 + 64) : 512;
    for (int kk0 = 0; kk0 < kend; kk0 += 64) {
        #pragma unroll
        for (int c = 0; c < 2; ++c) {
            int ch = c * 256 + tid;
            int r = ch >> 3, gs = (ch & 7) ^ (r & 7);
            GLOAD16(Kb + ((size_t)(b * 512 + kk0 + r) * 512 + h * 64 + gs * 8),
                    Ks + ch * 8);
            GLOAD16(VbT + ((size_t)((b * 8 + h) * 64 + r) * 512 + kk0 + gs * 8),
                    Vs + ch * 8);
        }
        __syncthreads();

        unsigned long long vm = __ballot(key_tok[b * 512 + kk0 + lane] != 0);

        f32x4 st[4];
        #pragma unroll
        for (int kt = 0; kt < 4; ++kt) {
            f32x4 s = {};
            #pragma unroll
            for (int ks = 0; ks < 2; ++ks) {
                int byte = ((kt * 16 + fr) * 128 + ks * 64 + kg * 16) ^ swz;
                bf16x8 kf = *reinterpret_cast<const bf16x8*>((const char*)Ks + byte);
                s = __builtin_amdgcn_mfma_f32_16x16x32_bf16(kf, qf[ks], s, 0, 0, 0);
            }
            st[kt] = s;
        }

        float sv[4][4];
        float mloc = -3.0e38f;
        #pragma unroll
        for (int kt = 0; kt < 4; ++kt)
            #pragma unroll
            for (int j = 0; j < 4; ++j) {
                int kl = kt * 16 + kg * 4 + j;
                float s = st[kt][j] * 0.125f;
                bool ok = (vm >> kl) & 1ull;
                if (causal && (kk0 + kl > qrow)) ok = false;
                s = ok ? s : -1e9f;
                sv[kt][j] = s;
                mloc = fmaxf(mloc, s);
            }
        mloc = fmaxf(mloc, __shfl_xor(mloc, 16));
        mloc = fmaxf(mloc, __shfl_xor(mloc, 32));
        float m_new = fmaxf(m_run, mloc);
        float scale = __expf(m_run - m_new);
        float ls = 0.f;
        #pragma unroll
        for (int kt = 0; kt < 4; ++kt)
            #pragma unroll
            for (int j = 0; j < 4; ++j) {
                float p = __expf(sv[kt][j] - m_new);
                sv[kt][j] = p;
                ls += p;
            }
        ls += __shfl_xor(ls, 16);
        ls += __shfl_xor(ls, 32);
        l_run = l_run * scale + ls;
        m_run = m_new;

        #pragma unroll
        for (int kt = 0; kt < 4; ++kt)
            #pragma unroll
            for (int c = 0; c < 2; ++c) {
                union { __bf16 hh[2]; unsigned u; } pk;
                pk.hh[0] = (__bf16)sv[kt][2 * c];
                pk.hh[1] = (__bf16)sv[kt][2 * c + 1];
                int byte = (fr * 128 + kt * 32 + kg * 8 + c * 4) ^ swz;
                *reinterpret_cast<unsigned*>((char*)pw + byte) = pk.u;
            }

        {
            int qb4 = kg * 4;
            float s0 = __shfl(scale, qb4 + 0), s1 = __shfl(scale, qb4 + 1);
            float s2 = __shfl(scale, qb4 + 2), s3 = __shfl(scale, qb4 + 3);
            #pragma unroll
            for (int nf = 0; nf < 4; ++nf) {
                po[nf][0] *= s0; po[nf][1] *= s1;
                po[nf][2] *= s2; po[nf][3] *= s3;
            }
        }

        #pragma unroll
        for (int ks2 = 0; ks2 < 2; ++ks2) {
            int pbyte = (fr * 128 + ks2 * 64 + kg * 16) ^ swz;
            bf16x8 pa = *reinterpret_cast<const bf16x8*>((const char*)pw + pbyte);
            #pragma unroll
            for (int nf = 0; nf < 4; ++nf) {
                int vbyte = ((nf * 16 + fr) * 128 + ks2 * 64 + kg * 16) ^ swz;
                bf16x8 vf = *reinterpret_cast<const bf16x8*>((const char*)Vs + vbyte);
                po[nf] = __builtin_amdgcn_mfma_f32_16x16x32_bf16(pa, vf, po[nf], 0, 0, 0);
            }
        }
        __syncthreads();
    }

    {
        int qb4 = kg * 4;
        float r0 = 1.0f / __shfl(l_run, qb4 + 0);
        float r1 = 1.0f / __shfl(l_run, qb4 + 1);
        float r2 = 1.0f / __shfl(l_run, qb4 + 2);
        float r3 = 1.0f / __shfl(l_run, qb4 + 3);
        #pragma unroll
        for (int nf = 0; nf < 4; ++nf) {
            size_t base = (size_t)(b * 512 + q0 + w * 16 + qb4) * 512 + h * 64 + nf * 16 + fr;
            Ob[base]           = (__bf16)(po[nf][0] * r0);
            Ob[base + 512]     = (__bf16)(po[nf][1] * r1);
            Ob[base + 1024]    = (__bf16)(po[nf][2] * r2);
            Ob[base + 1536]    = (__bf16)(po[nf][3] * r3);
        }
    }
}

// ---------------------------------------------------------------- residual + LN (+ bf16 copy)
__global__ __launch_bounds__(256) void add_ln_k(float* __restrict__ x,
                                                const float* __restrict__ a,
                                                const float* __restrict__ g,
                                                const float* __restrict__ bb,
                                                __bf16* __restrict__ xb)
{
    int row = blockIdx.x;
    size_t base = (size_t)row * Dm;
    int tid = threadIdx.x;
    float v0 = x[base + tid]       + a[base + tid];
    float v1 = x[base + tid + 256] + a[base + tid + 256];
    float s  = v0 + v1;
    float s2 = v0 * v0 + v1 * v1;
    #pragma unroll
    for (int o = 1; o < 64; o <<= 1) {
        s  += __shfl_xor(s, o);
        s2 += __shfl_xor(s2, o);
    }
    __shared__ float red[8];
    int wid = tid >> 6, lane = tid & 63;
    if (lane == 0) { red[wid] = s; red[wid + 4] = s2; }
    __syncthreads();
    s  = red[0] + red[1] + red[2] + red[3];
    s2 = red[4] + red[5] + red[6] + red[7];
    float mean = s * (1.0f / 512.0f);
    float var  = s2 * (1.0f / 512.0f) - mean * mean;
    float rstd = rsqrtf(var + 1e-5f);
    float y0 = (v0 - mean) * rstd * g[tid]       + bb[tid];
    float y1 = (v1 - mean) * rstd * g[tid + 256] + bb[tid + 256];
    x[base + tid]        = y0;
    x[base + tid + 256]  = y1;
    xb[base + tid]       = (__bf16)y0;
    xb[base + tid + 256] = (__bf16)y1;
}

// ---------------------------------------------------------------- launch
extern "C" void kernel_launch(void* const* d_in, const int* in_sizes, int n_in,
                              void* d_out, int out_size, void* d_ws, size_t ws_size,
                              hipStream_t stream)
{
    const int*   src        = (const int*)  d_in[0];
    const int*   tgt        = (const int*)  d_in[1];
    const float* src_emb    = (const float*)d_in[2];
    const float* tgt_emb    = (const float*)d_in[3];
    const float* enc_attn_w = (const float*)d_in[4];
    const float* enc_attn_b = (const float*)d_in[5];
    const float* enc_ffn_w1 = (const float*)d_in[6];
    const float* enc_ffn_b1 = (const float*)d_in[7];
    const float* enc_ffn_w2 = (const float*)d_in[8];
    const float* enc_ffn_b2 = (const float*)d_in[9];
    const float* enc_ln_g   = (const float*)d_in[10];
    const float* enc_ln_b   = (const float*)d_in[11];
    const float* dec_self_w = (const float*)d_in[12];
    const float* dec_self_b = (const float*)d_in[13];
    const float* dec_cross_w= (const float*)d_in[14];
    const float* dec_cross_b= (const float*)d_in[15];
    const float* dec_ffn_w1 = (const float*)d_in[16];
    const float* dec_ffn_b1 = (const float*)d_in[17];
    const float* dec_ffn_w2 = (const float*)d_in[18];
    const float* dec_ffn_b2 = (const float*)d_in[19];
    const float* dec_ln_g   = (const float*)d_in[20];
    const float* dec_ln_b   = (const float*)d_in[21];
    const float* out_w      = (const float*)d_in[22];
    const float* out_b      = (const float*)d_in[23];

    const size_t NROW = (size_t)NTOK * Dm;        // 2,097,152
    const size_t NH1  = (size_t)NTOK * DFFv;      // 8,388,608

    float* ws  = (float*)d_ws;
    float* xe  = ws;            // f32 encoder stream
    float* xd  = xe + NROW;     // f32 decoder stream
    float* t0  = xd + NROW;     // f32 sublayer output (pre-LN)

    __bf16* xeb  = (__bf16*)(t0 + NROW);
    __bf16* xdb  = xeb + NROW;
    __bf16* qbb  = xdb + NROW;
    __bf16* kbb  = qbb + NROW;
    __bf16* vbT  = kbb + NROW;            // [(b*8+h)*64+f][512]
    __bf16* ctxb = vbT + NROW;
    __bf16* h1b  = ctxb + NROW;           // [4096,2048] bf16

    const size_t WSZ  = (size_t)Dm * Dm;          // 262144
    const size_t FSZ  = (size_t)Dm * DFFv;        // 1048576
    __bf16* w_enc_attn = h1b + NH1;
    __bf16* w_enc_f1   = w_enc_attn + 24 * WSZ;
    __bf16* w_enc_f2   = w_enc_f1 + 6 * FSZ;
    __bf16* w_dec_self = w_enc_f2 + 6 * FSZ;
    __bf16* w_dec_cross= w_dec_self + 24 * WSZ;
    __bf16* w_dec_f1   = w_dec_cross + 24 * WSZ;
    __bf16* w_dec_f2   = w_dec_f1 + 6 * FSZ;
    __bf16* w_out      = w_dec_f2 + 6 * FSZ;      // 512*32000

    // ---- weight transpose+convert
    wtr_k<<<dim3(Dm / 32, Dm / 32, 24), 256, 0, stream>>>(enc_attn_w, w_enc_attn, Dm, Dm);
    wtr_k<<<dim3(DFFv / 32, Dm / 32, 6), 256, 0, stream>>>(enc_ffn_w1, w_enc_f1, Dm, DFFv);
    wtr_k<<<dim3(Dm / 32, DFFv / 32, 6), 256, 0, stream>>>(enc_ffn_w2, w_enc_f2, DFFv, Dm);
    wtr_k<<<dim3(Dm / 32, Dm / 32, 24), 256, 0, stream>>>(dec_self_w, w_dec_self, Dm, Dm);
    wtr_k<<<dim3(Dm / 32, Dm / 32, 24), 256, 0, stream>>>(dec_cross_w, w_dec_cross, Dm, Dm);
    wtr_k<<<dim3(DFFv / 32, Dm / 32, 6), 256, 0, stream>>>(dec_ffn_w1, w_dec_f1, Dm, DFFv);
    wtr_k<<<dim3(Dm / 32, DFFv / 32, 6), 256, 0, stream>>>(dec_ffn_w2, w_dec_f2, DFFv, Dm);
    wtr_k<<<dim3(Vv / 32, Dm / 32, 1), 256, 0, stream>>>(out_w, w_out, Dm, Vv);

    auto gqkv = [&](const __bf16* A, const __bf16* Wt, const float* bias) {
        gemm_mfma_k<128, 0, 2><<<dim3(1536 / 128, NTOK / 128), 256, 0, stream>>>(
            A, Wt, bias, qbb, kbb, vbT, NTOK, 1536, Dm);
    };
    auto gkv = [&](const __bf16* A, const __bf16* Wt, const float* bias) {
        gemm_mfma_k<128, 0, 3><<<dim3(1024 / 128, NTOK / 128), 256, 0, stream>>>(
            A, Wt, bias, kbb, nullptr, vbT, NTOK, 1024, Dm);
    };
    auto g64f = [&](const __bf16* A, const __bf16* Wt, const float* bias, float* C, int K) {
        gemm_mfma_k<64, 0, 0><<<dim3(Dm / 64, NTOK / 128), 256, 0, stream>>>(
            A, Wt, bias, C, nullptr, nullptr, NTOK, Dm, K);
    };
    auto g64b = [&](const __bf16* A, const __bf16* Wt, const float* bias, __bf16* C, int K) {
        gemm_mfma_k<64, 0, 1><<<dim3(Dm / 64, NTOK / 128), 256, 0, stream>>>(
            A, Wt, bias, C, nullptr, nullptr, NTOK, Dm, K);
    };
    auto attn = [&](const __bf16* Q, const __bf16* K, const __bf16* Vt, __bf16* O,
                    const int* kt, int causal) {
        attn_mfma_k<<<dim3(Ss / 64, Hh, Bb), 256, 0, stream>>>(Q, K, Vt, O, kt, causal);
    };
    auto lnorm = [&](float* x, const float* a, const float* g, const float* b, __bf16* xb) {
        add_ln_k<<<NTOK, 256, 0, stream>>>(x, a, g, b, xb);
    };

    // embeddings + PE
    embed_pe_k<<<NTOK, 256, 0, stream>>>(src, src_emb, xe, xeb, Ss);
    embed_pe_k<<<NTOK, 256, 0, stream>>>(tgt, tgt_emb, xd, xdb, Ss);

    // ---------------- encoder
    for (int i = 0; i < Ll; ++i) {
        const __bf16* W = w_enc_attn + (size_t)i * 4 * WSZ;
        const float* Bv = enc_attn_b + (size_t)i * 4 * Dm;
        gqkv(xeb, W, Bv);                               // q,k,v (+V transposed)
        attn(qbb, kbb, vbT, ctxb, src, 0);
        g64f(ctxb, W + 3 * WSZ, Bv + 3 * Dm, t0, Dm);
        lnorm(xe, t0, enc_ln_g + i * 2 * Dm, enc_ln_b + i * 2 * Dm, xeb);
        gemm_mfma_k<128, 1, 1><<<dim3(DFFv / 128, NTOK / 128), 256, 0, stream>>>(
            xeb, w_enc_f1 + (size_t)i * FSZ, enc_ffn_b1 + i * DFFv, h1b, nullptr, nullptr,
            NTOK, DFFv, Dm);
        g64f(h1b, w_enc_f2 + (size_t)i * FSZ, enc_ffn_b2 + i * Dm, t0, DFFv);
        lnorm(xe, t0, enc_ln_g + i * 2 * Dm + Dm, enc_ln_b + i * 2 * Dm + Dm, xeb);
    }

    // ---------------- decoder
    for (int i = 0; i < Ll; ++i) {
        const __bf16* Wsf = w_dec_self + (size_t)i * 4 * WSZ;
        const float* Bsf = dec_self_b + (size_t)i * 4 * Dm;
        gqkv(xdb, Wsf, Bsf);
        attn(qbb, kbb, vbT, ctxb, tgt, 1);                   // causal + tgt pad
        g64f(ctxb, Wsf + 3 * WSZ, Bsf + 3 * Dm, t0, Dm);
        lnorm(xd, t0, dec_ln_g + i * 3 * Dm, dec_ln_b + i * 3 * Dm, xdb);

        const __bf16* Wc = w_dec_cross + (size_t)i * 4 * WSZ;
        const float* Bc = dec_cross_b + (size_t)i * 4 * Dm;
        g64b(xdb, Wc + 0 * WSZ, Bc + 0 * Dm, qbb, Dm);       // Q from decoder
        gkv(xeb, Wc + 1 * WSZ, Bc + 1 * Dm);                 // K,V from encoder memory
        attn(qbb, kbb, vbT, ctxb, src, 0);                   // src pad
        g64f(ctxb, Wc + 3 * WSZ, Bc + 3 * Dm, t0, Dm);
        lnorm(xd, t0, dec_ln_g + i * 3 * Dm + Dm, dec_ln_b + i * 3 * Dm + Dm, xdb);

        gemm_mfma_k<128, 1, 1><<<dim3(DFFv / 128, NTOK / 128), 256, 0, stream>>>(
            xdb, w_dec_f1 + (size_t)i * FSZ, dec_ffn_b1 + i * DFFv, h1b, nullptr, nullptr,
            NTOK, DFFv, Dm);
        g64f(h1b, w_dec_f2 + (size_t)i * FSZ, dec_ffn_b2 + i * Dm, t0, DFFv);
        lnorm(xd, t0, dec_ln_g + i * 3 * Dm + 2 * Dm, dec_ln_b + i * 3 * Dm + 2 * Dm, xdb);
    }

    // ---------------- final vocab projection -> d_out [8,512,32000] f32
    gemm_mfma_k<128, 0, 0><<<dim3(Vv / 128, NTOK / 128), 256, 0, stream>>>(
        xdb, w_out, out_b, d_out, nullptr, nullptr, NTOK, Vv, Dm);
}

// Round 5
// 2349.780 us; speedup vs baseline: 10.7617x; 1.0852x over previous
//
#include <hip/hip_runtime.h>
#include <hip/hip_bf16.h>

// TransformerNMT r4: BM=64 high-occupancy tiles for small GEMMs, KVBLK=128
// attention (half the barriers), 128x256 vocab GEMM tile.
// B=8, S=T=512, D=512, H=8, hd=64, L=6, DFF=2048, V=32000, PAD=0

#define Dm 512
#define Hh 8
#define HD 64
#define Ll 6
#define DFFv 2048
#define Vv 32000
#define Bb 8
#define Ss 512
#define NTOK (Bb * Ss)   // 4096 rows

typedef __bf16 bf16x8 __attribute__((ext_vector_type(8)));
typedef __bf16 bf16x4 __attribute__((ext_vector_type(4)));
typedef float  f32x4  __attribute__((ext_vector_type(4)));

#define GLOAD16(gp, lp) __builtin_amdgcn_global_load_lds( \
    (const __attribute__((address_space(1))) unsigned int*)(const void*)(gp), \
    (__attribute__((address_space(3))) unsigned int*)(void*)(lp), 16, 0, 0)

// ---------------------------------------------------------------- embed + PE (f32 + bf16 out)
__global__ void embed_pe_k(const int* __restrict__ tok, const float* __restrict__ emb,
                           float* __restrict__ out, __bf16* __restrict__ outb, int Slen)
{
    int row = blockIdx.x;
    int s = row % Slen;
    int t = tok[row];
    const float* e = emb + (size_t)t * Dm;
    float* o = out + (size_t)row * Dm;
    __bf16* ob = outb + (size_t)row * Dm;
    for (int dd = threadIdx.x; dd < Dm; dd += blockDim.x) {
        int j = dd >> 1;
        float div = expf((float)(2 * j) * (-9.210340371976184f / 512.0f));
        float ang = (float)s * div;
        float pe = (dd & 1) ? cosf(ang) : sinf(ang);
        float v = e[dd] * 22.627416997969522f + pe;   // sqrt(512)
        o[dd] = v;
        ob[dd] = (__bf16)v;
    }
}

// ---------------------------------------------------------------- weight transpose+convert
__global__ __launch_bounds__(256) void wtr_k(const float* __restrict__ W,
                                             __bf16* __restrict__ Wt, int K, int N)
{
    __shared__ float t[32][33];
    size_t msz = (size_t)K * N;
    const float* Wm = W + (size_t)blockIdx.z * msz;
    __bf16* Wtm = Wt + (size_t)blockIdx.z * msz;
    int n0 = blockIdx.x * 32, k0 = blockIdx.y * 32;
    int r = threadIdx.x >> 3, c4 = (threadIdx.x & 7) * 4;
    float4 v = *reinterpret_cast<const float4*>(&Wm[(size_t)(k0 + r) * N + n0 + c4]);
    t[r][c4] = v.x; t[r][c4 + 1] = v.y; t[r][c4 + 2] = v.z; t[r][c4 + 3] = v.w;
    __syncthreads();
    int n = threadIdx.x >> 3, kq = (threadIdx.x & 7) * 4;
    bf16x4 o;
    o[0] = (__bf16)t[kq + 0][n]; o[1] = (__bf16)t[kq + 1][n];
    o[2] = (__bf16)t[kq + 2][n]; o[3] = (__bf16)t[kq + 3][n];
    *reinterpret_cast<bf16x4*>(&Wtm[(size_t)(n0 + n) * K + k0 + kq]) = o;
}

// ---------------------------------------------------------------- MFMA GEMM
// C[M,N] = A[M,K](bf16) @ Wt[N,K](bf16)^T + bias.
// MODE 0: f32 out; MODE 1: bf16 out (+RELU); MODE 2: fused QKV (N=1536);
// MODE 3: fused KV (N=1024). vT: [((b*8+h)*64+f)*512 + s].
template<int BM, int BN, int RELU, int MODE>
__global__ __launch_bounds__(256) void gemm_mfma_k(const __bf16* __restrict__ A,
                                                   const __bf16* __restrict__ Wt,
                                                   const float* __restrict__ bias,
                                                   void* __restrict__ Cout,
                                                   __bf16* __restrict__ out_k,
                                                   __bf16* __restrict__ out_vT,
                                                   int M, int N, int K)
{
    constexpr int NF_M = BM / 32;
    constexpr int NF_N = BN / 32;
    __shared__ __bf16 As[BM * 32];
    __shared__ __bf16 Bs[BN * 32];
    const int tid = threadIdx.x;
    const int wave = tid >> 6, lane = tid & 63;
    const int wr = wave >> 1, wc = wave & 1;
    const int row0 = blockIdx.y * BM, col0 = blockIdx.x * BN;

    f32x4 acc[NF_M][NF_N] = {};

    const int rsub = lane >> 2;
    const int kel  = (lane & 3) * 8;
    const int fr   = lane & 15;
    const int kg   = lane >> 4;

    for (int k0 = 0; k0 < K; k0 += 32) {
        #pragma unroll
        for (int cc = 0; cc < BM / 64; ++cc) {
            int c = wave * (BM / 64) + cc;
            GLOAD16(A + (size_t)(row0 + c * 16 + rsub) * K + k0 + kel,
                    As + c * 512 + lane * 8);
        }
        #pragma unroll
        for (int cc = 0; cc < BN / 64; ++cc) {
            int c = wave * (BN / 64) + cc;
            GLOAD16(Wt + (size_t)(col0 + c * 16 + rsub) * K + k0 + kel,
                    Bs + c * 512 + lane * 8);
        }
        __syncthreads();

        const bf16x8* Av = reinterpret_cast<const bf16x8*>(As);
        const bf16x8* Bv = reinterpret_cast<const bf16x8*>(Bs);
        bf16x8 af[NF_M], bq[NF_N];
        #pragma unroll
        for (int m = 0; m < NF_M; ++m)
            af[m] = Av[(wr * (BM / 2) + m * 16 + fr) * 4 + kg];
        #pragma unroll
        for (int n = 0; n < NF_N; ++n)
            bq[n] = Bv[(wc * (BN / 2) + n * 16 + fr) * 4 + kg];
        #pragma unroll
        for (int m = 0; m < NF_M; ++m)
            #pragma unroll
            for (int n = 0; n < NF_N; ++n)
                acc[m][n] = __builtin_amdgcn_mfma_f32_16x16x32_bf16(
                    af[m], bq[n], acc[m][n], 0, 0, 0);
        __syncthreads();
    }

    #pragma unroll
    for (int m = 0; m < NF_M; ++m) {
        #pragma unroll
        for (int n = 0; n < NF_N; ++n) {
            int colg = col0 + wc * (BN / 2) + n * 16 + fr;
            float bv = bias[colg];
            #pragma unroll
            for (int j = 0; j < 4; ++j) {
                int row = row0 + wr * (BM / 2) + m * 16 + kg * 4 + j;
                float v = acc[m][n][j] + bv;
                if (RELU) v = fmaxf(v, 0.f);
                if constexpr (MODE == 0) {
                    ((float*)Cout)[(size_t)row * N + colg] = v;
                } else if constexpr (MODE == 1) {
                    ((__bf16*)Cout)[(size_t)row * N + colg] = (__bf16)v;
                } else {
                    int seg = colg >> 9;          // uniform per block
                    int c = colg & 511;
                    bool isV = (MODE == 2) ? (seg == 2) : (seg == 1);
                    if (!isV) {
                        __bf16* o = (MODE == 2 && seg == 1) ? out_k : (__bf16*)Cout;
                        o[(size_t)row * 512 + c] = (__bf16)v;
                    } else {
                        int bi = row >> 9, s = row & 511;
                        int hh = c >> 6, f = c & 63;
                        out_vT[(size_t)((bi * 8 + hh) * 64 + f) * 512 + s] = (__bf16)v;
                    }
                }
            }
        }
    }
}

// ---------------------------------------------------------------- MFMA flash attention
// KVBLK=128. Qb,Kb: [4096][512] bf16; VbT: [(b*8+h)*64+f][512]; Ob: [4096][512] bf16.
__global__ __launch_bounds__(256) void attn_mfma_k(const __bf16* __restrict__ Qb,
                                                   const __bf16* __restrict__ Kb,
                                                   const __bf16* __restrict__ VbT,
                                                   __bf16* __restrict__ Ob,
                                                   const int* __restrict__ key_tok,
                                                   int causal)
{
    __shared__ __bf16 Ks[128 * 64];     // [key][feat], 128B rows, swizzled
    __shared__ __bf16 Vs[64 * 128];     // [feat][key], 256B rows, swizzled
    __shared__ __bf16 Pl[4][16 * 128];  // per-wave P, 256B rows, swizzled

    const int tid = threadIdx.x;
    const int w = tid >> 6, lane = tid & 63;
    const int fr = lane & 15, kg = lane >> 4;
    const int q0 = blockIdx.x * 64;
    const int h = blockIdx.y, b = blockIdx.z;
    const int qrow = q0 + w * 16 + fr;
    const int swz = (fr & 7) << 4;

    bf16x8 qf[2];
    {
        const __bf16* qp = Qb + ((size_t)(b * 512 + qrow) * 512 + h * 64 + kg * 8);
        qf[0] = *reinterpret_cast<const bf16x8*>(qp);
        qf[1] = *reinterpret_cast<const bf16x8*>(qp + 32);
    }

    f32x4 po[4] = {};
    float m_run = -3.0e38f, l_run = 0.f;
    __bf16* pw = Pl[w];

    const int kkend = causal ? ((q0 + 64 + 127) & ~127) : 512;
    for (int kk0 = 0; kk0 < kkend; kk0 += 128) {
        // ---- stage K [128][64] and V [64][128] (inverse-swizzled global source)
        #pragma unroll
        for (int c = 0; c < 4; ++c) {
            int ch = c * 256 + tid;               // 0..1023 (16B groups)
            int r = ch >> 3, gsk = (ch & 7) ^ (r & 7);
            GLOAD16(Kb + ((size_t)(b * 512 + kk0 + r) * 512 + h * 64 + gsk * 8),
                    Ks + ch * 8);
            int f = ch >> 4, gsv = (ch & 15) ^ (f & 7);
            GLOAD16(VbT + ((size_t)((b * 8 + h) * 64 + f) * 512 + kk0 + gsv * 8),
                    Vs + ch * 8);
        }
        __syncthreads();

        unsigned long long vm0 = __ballot(key_tok[b * 512 + kk0 + lane] != 0);
        unsigned long long vm1 = __ballot(key_tok[b * 512 + kk0 + 64 + lane] != 0);

        // ---- S^T = K @ Q^T
        f32x4 st[8];
        #pragma unroll
        for (int kt = 0; kt < 8; ++kt) {
            f32x4 s = {};
            #pragma unroll
            for (int ks = 0; ks < 2; ++ks) {
                int byte = ((kt * 16 + fr) * 128 + ks * 64 + kg * 16) ^ swz;
                bf16x8 kf = *reinterpret_cast<const bf16x8*>((const char*)Ks + byte);
                s = __builtin_amdgcn_mfma_f32_16x16x32_bf16(kf, qf[ks], s, 0, 0, 0);
            }
            st[kt] = s;
        }

        // ---- mask + online softmax
        float sv[8][4];
        float mloc = -3.0e38f;
        #pragma unroll
        for (int kt = 0; kt < 8; ++kt) {
            unsigned long long vm = (kt < 4) ? vm0 : vm1;
            #pragma unroll
            for (int j = 0; j < 4; ++j) {
                int kl = kt * 16 + kg * 4 + j;
                float s = st[kt][j] * 0.125f;
                bool ok = (vm >> (kl & 63)) & 1ull;
                if (causal && (kk0 + kl > qrow)) ok = false;
                s = ok ? s : -1e9f;
                sv[kt][j] = s;
                mloc = fmaxf(mloc, s);
            }
        }
        mloc = fmaxf(mloc, __shfl_xor(mloc, 16));
        mloc = fmaxf(mloc, __shfl_xor(mloc, 32));
        float m_new = fmaxf(m_run, mloc);
        float scale = __expf(m_run - m_new);
        float ls = 0.f;
        #pragma unroll
        for (int kt = 0; kt < 8; ++kt)
            #pragma unroll
            for (int j = 0; j < 4; ++j) {
                float p = __expf(sv[kt][j] - m_new);
                sv[kt][j] = p;
                ls += p;
            }
        ls += __shfl_xor(ls, 16);
        ls += __shfl_xor(ls, 32);
        l_run = l_run * scale + ls;
        m_run = m_new;

        // ---- P -> per-wave LDS (256B rows, swizzled)
        #pragma unroll
        for (int kt = 0; kt < 8; ++kt)
            #pragma unroll
            for (int c = 0; c < 2; ++c) {
                union { __bf16 hh[2]; unsigned u; } pk;
                pk.hh[0] = (__bf16)sv[kt][2 * c];
                pk.hh[1] = (__bf16)sv[kt][2 * c + 1];
                int byte = (fr * 256 + kt * 32 + kg * 8 + c * 4) ^ swz;
                *reinterpret_cast<unsigned*>((char*)pw + byte) = pk.u;
            }

        // ---- rescale O
        {
            int qb4 = kg * 4;
            float s0 = __shfl(scale, qb4 + 0), s1 = __shfl(scale, qb4 + 1);
            float s2 = __shfl(scale, qb4 + 2), s3 = __shfl(scale, qb4 + 3);
            #pragma unroll
            for (int nf = 0; nf < 4; ++nf) {
                po[nf][0] *= s0; po[nf][1] *= s1;
                po[nf][2] *= s2; po[nf][3] *= s3;
            }
        }

        // ---- PV: O += P @ V
        #pragma unroll
        for (int ks2 = 0; ks2 < 4; ++ks2) {
            int pbyte = (fr * 256 + ks2 * 64 + kg * 16) ^ swz;
            bf16x8 pa = *reinterpret_cast<const bf16x8*>((const char*)pw + pbyte);
            #pragma unroll
            for (int nf = 0; nf < 4; ++nf) {
                int vbyte = ((nf * 16 + fr) * 256 + ks2 * 64 + kg * 16) ^ swz;
                bf16x8 vf = *reinterpret_cast<const bf16x8*>((const char*)Vs + vbyte);
                po[nf] = __builtin_amdgcn_mfma_f32_16x16x32_bf16(pa, vf, po[nf], 0, 0, 0);
            }
        }
        __syncthreads();
    }

    {
        int qb4 = kg * 4;
        float r0 = 1.0f / __shfl(l_run, qb4 + 0);
        float r1 = 1.0f / __shfl(l_run, qb4 + 1);
        float r2 = 1.0f / __shfl(l_run, qb4 + 2);
        float r3 = 1.0f / __shfl(l_run, qb4 + 3);
        #pragma unroll
        for (int nf = 0; nf < 4; ++nf) {
            size_t base = (size_t)(b * 512 + q0 + w * 16 + qb4) * 512 + h * 64 + nf * 16 + fr;
            Ob[base]           = (__bf16)(po[nf][0] * r0);
            Ob[base + 512]     = (__bf16)(po[nf][1] * r1);
            Ob[base + 1024]    = (__bf16)(po[nf][2] * r2);
            Ob[base + 1536]    = (__bf16)(po[nf][3] * r3);
        }
    }
}

// ---------------------------------------------------------------- residual + LN (+ bf16 copy)
__global__ __launch_bounds__(256) void add_ln_k(float* __restrict__ x,
                                                const float* __restrict__ a,
                                                const float* __restrict__ g,
                                                const float* __restrict__ bb,
                                                __bf16* __restrict__ xb)
{
    int row = blockIdx.x;
    size_t base = (size_t)row * Dm;
    int tid = threadIdx.x;
    float v0 = x[base + tid]       + a[base + tid];
    float v1 = x[base + tid + 256] + a[base + tid + 256];
    float s  = v0 + v1;
    float s2 = v0 * v0 + v1 * v1;
    #pragma unroll
    for (int o = 1; o < 64; o <<= 1) {
        s  += __shfl_xor(s, o);
        s2 += __shfl_xor(s2, o);
    }
    __shared__ float red[8];
    int wid = tid >> 6, lane = tid & 63;
    if (lane == 0) { red[wid] = s; red[wid + 4] = s2; }
    __syncthreads();
    s  = red[0] + red[1] + red[2] + red[3];
    s2 = red[4] + red[5] + red[6] + red[7];
    float mean = s * (1.0f / 512.0f);
    float var  = s2 * (1.0f / 512.0f) - mean * mean;
    float rstd = rsqrtf(var + 1e-5f);
    float y0 = (v0 - mean) * rstd * g[tid]       + bb[tid];
    float y1 = (v1 - mean) * rstd * g[tid + 256] + bb[tid + 256];
    x[base + tid]        = y0;
    x[base + tid + 256]  = y1;
    xb[base + tid]       = (__bf16)y0;
    xb[base + tid + 256] = (__bf16)y1;
}

// ---------------------------------------------------------------- launch
extern "C" void kernel_launch(void* const* d_in, const int* in_sizes, int n_in,
                              void* d_out, int out_size, void* d_ws, size_t ws_size,
                              hipStream_t stream)
{
    const int*   src        = (const int*)  d_in[0];
    const int*   tgt        = (const int*)  d_in[1];
    const float* src_emb    = (const float*)d_in[2];
    const float* tgt_emb    = (const float*)d_in[3];
    const float* enc_attn_w = (const float*)d_in[4];
    const float* enc_attn_b = (const float*)d_in[5];
    const float* enc_ffn_w1 = (const float*)d_in[6];
    const float* enc_ffn_b1 = (const float*)d_in[7];
    const float* enc_ffn_w2 = (const float*)d_in[8];
    const float* enc_ffn_b2 = (const float*)d_in[9];
    const float* enc_ln_g   = (const float*)d_in[10];
    const float* enc_ln_b   = (const float*)d_in[11];
    const float* dec_self_w = (const float*)d_in[12];
    const float* dec_self_b = (const float*)d_in[13];
    const float* dec_cross_w= (const float*)d_in[14];
    const float* dec_cross_b= (const float*)d_in[15];
    const float* dec_ffn_w1 = (const float*)d_in[16];
    const float* dec_ffn_b1 = (const float*)d_in[17];
    const float* dec_ffn_w2 = (const float*)d_in[18];
    const float* dec_ffn_b2 = (const float*)d_in[19];
    const float* dec_ln_g   = (const float*)d_in[20];
    const float* dec_ln_b   = (const float*)d_in[21];
    const float* out_w      = (const float*)d_in[22];
    const float* out_b      = (const float*)d_in[23];

    const size_t NROW = (size_t)NTOK * Dm;        // 2,097,152
    const size_t NH1  = (size_t)NTOK * DFFv;      // 8,388,608

    float* ws  = (float*)d_ws;
    float* xe  = ws;            // f32 encoder stream
    float* xd  = xe + NROW;     // f32 decoder stream
    float* t0  = xd + NROW;     // f32 sublayer output (pre-LN)

    __bf16* xeb  = (__bf16*)(t0 + NROW);
    __bf16* xdb  = xeb + NROW;
    __bf16* qbb  = xdb + NROW;
    __bf16* kbb  = qbb + NROW;
    __bf16* vbT  = kbb + NROW;            // [(b*8+h)*64+f][512]
    __bf16* ctxb = vbT + NROW;
    __bf16* h1b  = ctxb + NROW;           // [4096,2048] bf16

    const size_t WSZ  = (size_t)Dm * Dm;          // 262144
    const size_t FSZ  = (size_t)Dm * DFFv;        // 1048576
    __bf16* w_enc_attn = h1b + NH1;
    __bf16* w_enc_f1   = w_enc_attn + 24 * WSZ;
    __bf16* w_enc_f2   = w_enc_f1 + 6 * FSZ;
    __bf16* w_dec_self = w_enc_f2 + 6 * FSZ;
    __bf16* w_dec_cross= w_dec_self + 24 * WSZ;
    __bf16* w_dec_f1   = w_dec_cross + 24 * WSZ;
    __bf16* w_dec_f2   = w_dec_f1 + 6 * FSZ;
    __bf16* w_out      = w_dec_f2 + 6 * FSZ;      // 512*32000

    // ---- weight transpose+convert
    wtr_k<<<dim3(Dm / 32, Dm / 32, 24), 256, 0, stream>>>(enc_attn_w, w_enc_attn, Dm, Dm);
    wtr_k<<<dim3(DFFv / 32, Dm / 32, 6), 256, 0, stream>>>(enc_ffn_w1, w_enc_f1, Dm, DFFv);
    wtr_k<<<dim3(Dm / 32, DFFv / 32, 6), 256, 0, stream>>>(enc_ffn_w2, w_enc_f2, DFFv, Dm);
    wtr_k<<<dim3(Dm / 32, Dm / 32, 24), 256, 0, stream>>>(dec_self_w, w_dec_self, Dm, Dm);
    wtr_k<<<dim3(Dm / 32, Dm / 32, 24), 256, 0, stream>>>(dec_cross_w, w_dec_cross, Dm, Dm);
    wtr_k<<<dim3(DFFv / 32, Dm / 32, 6), 256, 0, stream>>>(dec_ffn_w1, w_dec_f1, Dm, DFFv);
    wtr_k<<<dim3(Dm / 32, DFFv / 32, 6), 256, 0, stream>>>(dec_ffn_w2, w_dec_f2, DFFv, Dm);
    wtr_k<<<dim3(Vv / 32, Dm / 32, 1), 256, 0, stream>>>(out_w, w_out, Dm, Vv);

    auto gqkv = [&](const __bf16* A, const __bf16* Wt, const float* bias) {
        gemm_mfma_k<64, 128, 0, 2><<<dim3(1536 / 128, NTOK / 64), 256, 0, stream>>>(
            A, Wt, bias, qbb, kbb, vbT, NTOK, 1536, Dm);
    };
    auto gkv = [&](const __bf16* A, const __bf16* Wt, const float* bias) {
        gemm_mfma_k<64, 128, 0, 3><<<dim3(1024 / 128, NTOK / 64), 256, 0, stream>>>(
            A, Wt, bias, kbb, nullptr, vbT, NTOK, 1024, Dm);
    };
    auto g64f = [&](const __bf16* A, const __bf16* Wt, const float* bias, float* C, int K) {
        gemm_mfma_k<64, 64, 0, 0><<<dim3(Dm / 64, NTOK / 64), 256, 0, stream>>>(
            A, Wt, bias, C, nullptr, nullptr, NTOK, Dm, K);
    };
    auto g64b = [&](const __bf16* A, const __bf16* Wt, const float* bias, __bf16* C, int K) {
        gemm_mfma_k<64, 64, 0, 1><<<dim3(Dm / 64, NTOK / 64), 256, 0, stream>>>(
            A, Wt, bias, C, nullptr, nullptr, NTOK, Dm, K);
    };
    auto attn = [&](const __bf16* Q, const __bf16* K, const __bf16* Vt, __bf16* O,
                    const int* kt, int causal) {
        attn_mfma_k<<<dim3(Ss / 64, Hh, Bb), 256, 0, stream>>>(Q, K, Vt, O, kt, causal);
    };
    auto lnorm = [&](float* x, const float* a, const float* g, const float* b, __bf16* xb) {
        add_ln_k<<<NTOK, 256, 0, stream>>>(x, a, g, b, xb);
    };

    // embeddings + PE
    embed_pe_k<<<NTOK, 256, 0, stream>>>(src, src_emb, xe, xeb, Ss);
    embed_pe_k<<<NTOK, 256, 0, stream>>>(tgt, tgt_emb, xd, xdb, Ss);

    // ---------------- encoder
    for (int i = 0; i < Ll; ++i) {
        const __bf16* W = w_enc_attn + (size_t)i * 4 * WSZ;
        const float* Bv = enc_attn_b + (size_t)i * 4 * Dm;
        gqkv(xeb, W, Bv);                               // q,k,v (+V transposed)
        attn(qbb, kbb, vbT, ctxb, src, 0);
        g64f(ctxb, W + 3 * WSZ, Bv + 3 * Dm, t0, Dm);
        lnorm(xe, t0, enc_ln_g + i * 2 * Dm, enc_ln_b + i * 2 * Dm, xeb);
        gemm_mfma_k<128, 128, 1, 1><<<dim3(DFFv / 128, NTOK / 128), 256, 0, stream>>>(
            xeb, w_enc_f1 + (size_t)i * FSZ, enc_ffn_b1 + i * DFFv, h1b, nullptr, nullptr,
            NTOK, DFFv, Dm);
        g64f(h1b, w_enc_f2 + (size_t)i * FSZ, enc_ffn_b2 + i * Dm, t0, DFFv);
        lnorm(xe, t0, enc_ln_g + i * 2 * Dm + Dm, enc_ln_b + i * 2 * Dm + Dm, xeb);
    }

    // ---------------- decoder
    for (int i = 0; i < Ll; ++i) {
        const __bf16* Wsf = w_dec_self + (size_t)i * 4 * WSZ;
        const float* Bsf = dec_self_b + (size_t)i * 4 * Dm;
        gqkv(xdb, Wsf, Bsf);
        attn(qbb, kbb, vbT, ctxb, tgt, 1);                   // causal + tgt pad
        g64f(ctxb, Wsf + 3 * WSZ, Bsf + 3 * Dm, t0, Dm);
        lnorm(xd, t0, dec_ln_g + i * 3 * Dm, dec_ln_b + i * 3 * Dm, xdb);

        const __bf16* Wc = w_dec_cross + (size_t)i * 4 * WSZ;
        const float* Bc = dec_cross_b + (size_t)i * 4 * Dm;
        g64b(xdb, Wc + 0 * WSZ, Bc + 0 * Dm, qbb, Dm);       // Q from decoder
        gkv(xeb, Wc + 1 * WSZ, Bc + 1 * Dm);                 // K,V from encoder memory
        attn(qbb, kbb, vbT, ctxb, src, 0);                   // src pad
        g64f(ctxb, Wc + 3 * WSZ, Bc + 3 * Dm, t0, Dm);
        lnorm(xd, t0, dec_ln_g + i * 3 * Dm + Dm, dec_ln_b + i * 3 * Dm + Dm, xdb);

        gemm_mfma_k<128, 128, 1, 1><<<dim3(DFFv / 128, NTOK / 128), 256, 0, stream>>>(
            xdb, w_dec_f1 + (size_t)i * FSZ, dec_ffn_b1 + i * DFFv, h1b, nullptr, nullptr,
            NTOK, DFFv, Dm);
        g64f(h1b, w_dec_f2 + (size_t)i * FSZ, dec_ffn_b2 + i * Dm, t0, DFFv);
        lnorm(xd, t0, dec_ln_g + i * 3 * Dm + 2 * Dm, dec_ln_b + i * 3 * Dm + 2 * Dm, xdb);
    }

    // ---------------- final vocab projection -> d_out [8,512,32000] f32
    gemm_mfma_k<128, 256, 0, 0><<<dim3(Vv / 256, NTOK / 128), 256, 0, stream>>>(
        xdb, w_out, out_b, d_out, nullptr, nullptr, NTOK, Vv, Dm);
}

// Round 6
// 2341.480 us; speedup vs baseline: 10.7999x; 1.0035x over previous
//
#include <hip/hip_runtime.h>
#include <hip/hip_bf16.h>

// TransformerNMT r5: M-fastest vocab grid (L2-resident weight panels),
// double-buffered single-barrier staging in GEMM + attention.
// B=8, S=T=512, D=512, H=8, hd=64, L=6, DFF=2048, V=32000, PAD=0

#define Dm 512
#define Hh 8
#define HD 64
#define Ll 6
#define DFFv 2048
#define Vv 32000
#define Bb 8
#define Ss 512
#define NTOK (Bb * Ss)   // 4096 rows

typedef __bf16 bf16x8 __attribute__((ext_vector_type(8)));
typedef __bf16 bf16x4 __attribute__((ext_vector_type(4)));
typedef float  f32x4  __attribute__((ext_vector_type(4)));

#define GLOAD16(gp, lp) __builtin_amdgcn_global_load_lds( \
    (const __attribute__((address_space(1))) unsigned int*)(const void*)(gp), \
    (__attribute__((address_space(3))) unsigned int*)(void*)(lp), 16, 0, 0)

// ---------------------------------------------------------------- embed + PE (f32 + bf16 out)
__global__ void embed_pe_k(const int* __restrict__ tok, const float* __restrict__ emb,
                           float* __restrict__ out, __bf16* __restrict__ outb, int Slen)
{
    int row = blockIdx.x;
    int s = row % Slen;
    int t = tok[row];
    const float* e = emb + (size_t)t * Dm;
    float* o = out + (size_t)row * Dm;
    __bf16* ob = outb + (size_t)row * Dm;
    for (int dd = threadIdx.x; dd < Dm; dd += blockDim.x) {
        int j = dd >> 1;
        float div = expf((float)(2 * j) * (-9.210340371976184f / 512.0f));
        float ang = (float)s * div;
        float pe = (dd & 1) ? cosf(ang) : sinf(ang);
        float v = e[dd] * 22.627416997969522f + pe;   // sqrt(512)
        o[dd] = v;
        ob[dd] = (__bf16)v;
    }
}

// ---------------------------------------------------------------- weight transpose+convert
__global__ __launch_bounds__(256) void wtr_k(const float* __restrict__ W,
                                             __bf16* __restrict__ Wt, int K, int N)
{
    __shared__ float t[32][33];
    size_t msz = (size_t)K * N;
    const float* Wm = W + (size_t)blockIdx.z * msz;
    __bf16* Wtm = Wt + (size_t)blockIdx.z * msz;
    int n0 = blockIdx.x * 32, k0 = blockIdx.y * 32;
    int r = threadIdx.x >> 3, c4 = (threadIdx.x & 7) * 4;
    float4 v = *reinterpret_cast<const float4*>(&Wm[(size_t)(k0 + r) * N + n0 + c4]);
    t[r][c4] = v.x; t[r][c4 + 1] = v.y; t[r][c4 + 2] = v.z; t[r][c4 + 3] = v.w;
    __syncthreads();
    int n = threadIdx.x >> 3, kq = (threadIdx.x & 7) * 4;
    bf16x4 o;
    o[0] = (__bf16)t[kq + 0][n]; o[1] = (__bf16)t[kq + 1][n];
    o[2] = (__bf16)t[kq + 2][n]; o[3] = (__bf16)t[kq + 3][n];
    *reinterpret_cast<bf16x4*>(&Wtm[(size_t)(n0 + n) * K + k0 + kq]) = o;
}

// ---------------------------------------------------------------- MFMA GEMM
// C[M,N] = A[M,K](bf16) @ Wt[N,K](bf16)^T + bias.
// MODE 0: f32 out; MODE 1: bf16 out (+RELU); MODE 2: fused QKV (N=1536);
// MODE 3: fused KV (N=1024). vT: [((b*8+h)*64+f)*512 + s].
// SWAPG: blockIdx.x = M-tile (M-fastest dispatch for L2 weight-panel reuse).
// Double-buffered LDS, one barrier per K-step.
template<int BM, int BN, int RELU, int MODE, int SWAPG>
__global__ __launch_bounds__(256) void gemm_mfma_k(const __bf16* __restrict__ A,
                                                   const __bf16* __restrict__ Wt,
                                                   const float* __restrict__ bias,
                                                   void* __restrict__ Cout,
                                                   __bf16* __restrict__ out_k,
                                                   __bf16* __restrict__ out_vT,
                                                   int M, int N, int K)
{
    constexpr int NF_M = BM / 32;
    constexpr int NF_N = BN / 32;
    __shared__ __bf16 As[2][BM * 32];
    __shared__ __bf16 Bs[2][BN * 32];
    const int tid = threadIdx.x;
    const int wave = tid >> 6, lane = tid & 63;
    const int wr = wave >> 1, wc = wave & 1;
    const int row0 = (SWAPG ? blockIdx.x : blockIdx.y) * BM;
    const int col0 = (SWAPG ? blockIdx.y : blockIdx.x) * BN;

    f32x4 acc[NF_M][NF_N] = {};

    const int rsub = lane >> 2;
    const int kel  = (lane & 3) * 8;
    const int fr   = lane & 15;
    const int kg   = lane >> 4;

    auto stage = [&](int buf, int k0) {
        #pragma unroll
        for (int cc = 0; cc < BM / 64; ++cc) {
            int c = wave * (BM / 64) + cc;
            GLOAD16(A + (size_t)(row0 + c * 16 + rsub) * K + k0 + kel,
                    &As[buf][c * 512 + lane * 8]);
        }
        #pragma unroll
        for (int cc = 0; cc < BN / 64; ++cc) {
            int c = wave * (BN / 64) + cc;
            GLOAD16(Wt + (size_t)(col0 + c * 16 + rsub) * K + k0 + kel,
                    &Bs[buf][c * 512 + lane * 8]);
        }
    };

    stage(0, 0);
    __syncthreads();                     // drains vmcnt -> tile 0 ready

    const int nk = K >> 5;
    for (int kb = 0; kb < nk; ++kb) {
        int cur = kb & 1;
        if (kb + 1 < nk) stage(cur ^ 1, (kb + 1) * 32);   // prefetch in flight

        const bf16x8* Av = reinterpret_cast<const bf16x8*>(As[cur]);
        const bf16x8* Bv = reinterpret_cast<const bf16x8*>(Bs[cur]);
        bf16x8 af[NF_M], bq[NF_N];
        #pragma unroll
        for (int m = 0; m < NF_M; ++m)
            af[m] = Av[(wr * (BM / 2) + m * 16 + fr) * 4 + kg];
        #pragma unroll
        for (int n = 0; n < NF_N; ++n)
            bq[n] = Bv[(wc * (BN / 2) + n * 16 + fr) * 4 + kg];
        #pragma unroll
        for (int m = 0; m < NF_M; ++m)
            #pragma unroll
            for (int n = 0; n < NF_N; ++n)
                acc[m][n] = __builtin_amdgcn_mfma_f32_16x16x32_bf16(
                    af[m], bq[n], acc[m][n], 0, 0, 0);
        __syncthreads();                 // prefetch drained + reads done
    }

    #pragma unroll
    for (int m = 0; m < NF_M; ++m) {
        #pragma unroll
        for (int n = 0; n < NF_N; ++n) {
            int colg = col0 + wc * (BN / 2) + n * 16 + fr;
            float bv = bias[colg];
            #pragma unroll
            for (int j = 0; j < 4; ++j) {
                int row = row0 + wr * (BM / 2) + m * 16 + kg * 4 + j;
                float v = acc[m][n][j] + bv;
                if (RELU) v = fmaxf(v, 0.f);
                if constexpr (MODE == 0) {
                    ((float*)Cout)[(size_t)row * N + colg] = v;
                } else if constexpr (MODE == 1) {
                    ((__bf16*)Cout)[(size_t)row * N + colg] = (__bf16)v;
                } else {
                    int seg = colg >> 9;          // uniform per block
                    int c = colg & 511;
                    bool isV = (MODE == 2) ? (seg == 2) : (seg == 1);
                    if (!isV) {
                        __bf16* o = (MODE == 2 && seg == 1) ? out_k : (__bf16*)Cout;
                        o[(size_t)row * 512 + c] = (__bf16)v;
                    } else {
                        int bi = row >> 9, s = row & 511;
                        int hh = c >> 6, f = c & 63;
                        out_vT[(size_t)((bi * 8 + hh) * 64 + f) * 512 + s] = (__bf16)v;
                    }
                }
            }
        }
    }
}

// ---------------------------------------------------------------- MFMA flash attention
// KVBLK=128, double-buffered K/V staging (one barrier per tile).
__global__ __launch_bounds__(256) void attn_mfma_k(const __bf16* __restrict__ Qb,
                                                   const __bf16* __restrict__ Kb,
                                                   const __bf16* __restrict__ VbT,
                                                   __bf16* __restrict__ Ob,
                                                   const int* __restrict__ key_tok,
                                                   int causal)
{
    __shared__ __bf16 Ks[2][128 * 64];     // [key][feat], 128B rows, swizzled
    __shared__ __bf16 Vs[2][64 * 128];     // [feat][key], 256B rows, swizzled
    __shared__ __bf16 Pl[4][16 * 128];     // per-wave P, 256B rows, swizzled

    const int tid = threadIdx.x;
    const int w = tid >> 6, lane = tid & 63;
    const int fr = lane & 15, kg = lane >> 4;
    const int q0 = blockIdx.x * 64;
    const int h = blockIdx.y, b = blockIdx.z;
    const int qrow = q0 + w * 16 + fr;
    const int swz = (fr & 7) << 4;

    bf16x8 qf[2];
    {
        const __bf16* qp = Qb + ((size_t)(b * 512 + qrow) * 512 + h * 64 + kg * 8);
        qf[0] = *reinterpret_cast<const bf16x8*>(qp);
        qf[1] = *reinterpret_cast<const bf16x8*>(qp + 32);
    }

    f32x4 po[4] = {};
    float m_run = -3.0e38f, l_run = 0.f;
    __bf16* pw = Pl[w];

    auto stage = [&](int buf, int kk0) {
        #pragma unroll
        for (int c = 0; c < 4; ++c) {
            int ch = c * 256 + tid;               // 0..1023 (16B groups)
            int r = ch >> 3, gsk = (ch & 7) ^ (r & 7);
            GLOAD16(Kb + ((size_t)(b * 512 + kk0 + r) * 512 + h * 64 + gsk * 8),
                    &Ks[buf][ch * 8]);
            int f = ch >> 4, gsv = (ch & 15) ^ (f & 7);
            GLOAD16(VbT + ((size_t)((b * 8 + h) * 64 + f) * 512 + kk0 + gsv * 8),
                    &Vs[buf][ch * 8]);
        }
    };

    const int kkend = causal ? ((q0 + 64 + 127) & ~127) : 512;
    stage(0, 0);
    __syncthreads();

    for (int kk0 = 0; kk0 < kkend; kk0 += 128) {
        int cur = (kk0 >> 7) & 1;
        if (kk0 + 128 < kkend) stage(cur ^ 1, kk0 + 128);   // prefetch in flight

        unsigned long long vm0 = __ballot(key_tok[b * 512 + kk0 + lane] != 0);
        unsigned long long vm1 = __ballot(key_tok[b * 512 + kk0 + 64 + lane] != 0);

        // ---- S^T = K @ Q^T
        f32x4 st[8];
        #pragma unroll
        for (int kt = 0; kt < 8; ++kt) {
            f32x4 s = {};
            #pragma unroll
            for (int ks = 0; ks < 2; ++ks) {
                int byte = ((kt * 16 + fr) * 128 + ks * 64 + kg * 16) ^ swz;
                bf16x8 kf = *reinterpret_cast<const bf16x8*>((const char*)Ks[cur] + byte);
                s = __builtin_amdgcn_mfma_f32_16x16x32_bf16(kf, qf[ks], s, 0, 0, 0);
            }
            st[kt] = s;
        }

        // ---- mask + online softmax
        float sv[8][4];
        float mloc = -3.0e38f;
        #pragma unroll
        for (int kt = 0; kt < 8; ++kt) {
            unsigned long long vm = (kt < 4) ? vm0 : vm1;
            #pragma unroll
            for (int j = 0; j < 4; ++j) {
                int kl = kt * 16 + kg * 4 + j;
                float s = st[kt][j] * 0.125f;
                bool ok = (vm >> (kl & 63)) & 1ull;
                if (causal && (kk0 + kl > qrow)) ok = false;
                s = ok ? s : -1e9f;
                sv[kt][j] = s;
                mloc = fmaxf(mloc, s);
            }
        }
        mloc = fmaxf(mloc, __shfl_xor(mloc, 16));
        mloc = fmaxf(mloc, __shfl_xor(mloc, 32));
        float m_new = fmaxf(m_run, mloc);
        float scale = __expf(m_run - m_new);
        float ls = 0.f;
        #pragma unroll
        for (int kt = 0; kt < 8; ++kt)
            #pragma unroll
            for (int j = 0; j < 4; ++j) {
                float p = __expf(sv[kt][j] - m_new);
                sv[kt][j] = p;
                ls += p;
            }
        ls += __shfl_xor(ls, 16);
        ls += __shfl_xor(ls, 32);
        l_run = l_run * scale + ls;
        m_run = m_new;

        // ---- P -> per-wave LDS (256B rows, swizzled)
        #pragma unroll
        for (int kt = 0; kt < 8; ++kt)
            #pragma unroll
            for (int c = 0; c < 2; ++c) {
                union { __bf16 hh[2]; unsigned u; } pk;
                pk.hh[0] = (__bf16)sv[kt][2 * c];
                pk.hh[1] = (__bf16)sv[kt][2 * c + 1];
                int byte = (fr * 256 + kt * 32 + kg * 8 + c * 4) ^ swz;
                *reinterpret_cast<unsigned*>((char*)pw + byte) = pk.u;
            }

        // ---- rescale O
        {
            int qb4 = kg * 4;
            float s0 = __shfl(scale, qb4 + 0), s1 = __shfl(scale, qb4 + 1);
            float s2 = __shfl(scale, qb4 + 2), s3 = __shfl(scale, qb4 + 3);
            #pragma unroll
            for (int nf = 0; nf < 4; ++nf) {
                po[nf][0] *= s0; po[nf][1] *= s1;
                po[nf][2] *= s2; po[nf][3] *= s3;
            }
        }

        // ---- PV: O += P @ V
        #pragma unroll
        for (int ks2 = 0; ks2 < 4; ++ks2) {
            int pbyte = (fr * 256 + ks2 * 64 + kg * 16) ^ swz;
            bf16x8 pa = *reinterpret_cast<const bf16x8*>((const char*)pw + pbyte);
            #pragma unroll
            for (int nf = 0; nf < 4; ++nf) {
                int vbyte = ((nf * 16 + fr) * 256 + ks2 * 64 + kg * 16) ^ swz;
                bf16x8 vf = *reinterpret_cast<const bf16x8*>((const char*)Vs[cur] + vbyte);
                po[nf] = __builtin_amdgcn_mfma_f32_16x16x32_bf16(pa, vf, po[nf], 0, 0, 0);
            }
        }
        __syncthreads();                 // prefetch drained + Ks/Vs reads done
    }

    {
        int qb4 = kg * 4;
        float r0 = 1.0f / __shfl(l_run, qb4 + 0);
        float r1 = 1.0f / __shfl(l_run, qb4 + 1);
        float r2 = 1.0f / __shfl(l_run, qb4 + 2);
        float r3 = 1.0f / __shfl(l_run, qb4 + 3);
        #pragma unroll
        for (int nf = 0; nf < 4; ++nf) {
            size_t base = (size_t)(b * 512 + q0 + w * 16 + qb4) * 512 + h * 64 + nf * 16 + fr;
            Ob[base]           = (__bf16)(po[nf][0] * r0);
            Ob[base + 512]     = (__bf16)(po[nf][1] * r1);
            Ob[base + 1024]    = (__bf16)(po[nf][2] * r2);
            Ob[base + 1536]    = (__bf16)(po[nf][3] * r3);
        }
    }
}

// ---------------------------------------------------------------- residual + LN (+ bf16 copy)
__global__ __launch_bounds__(256) void add_ln_k(float* __restrict__ x,
                                                const float* __restrict__ a,
                                                const float* __restrict__ g,
                                                const float* __restrict__ bb,
                                                __bf16* __restrict__ xb)
{
    int row = blockIdx.x;
    size_t base = (size_t)row * Dm;
    int tid = threadIdx.x;
    float v0 = x[base + tid]       + a[base + tid];
    float v1 = x[base + tid + 256] + a[base + tid + 256];
    float s  = v0 + v1;
    float s2 = v0 * v0 + v1 * v1;
    #pragma unroll
    for (int o = 1; o < 64; o <<= 1) {
        s  += __shfl_xor(s, o);
        s2 += __shfl_xor(s2, o);
    }
    __shared__ float red[8];
    int wid = tid >> 6, lane = tid & 63;
    if (lane == 0) { red[wid] = s; red[wid + 4] = s2; }
    __syncthreads();
    s  = red[0] + red[1] + red[2] + red[3];
    s2 = red[4] + red[5] + red[6] + red[7];
    float mean = s * (1.0f / 512.0f);
    float var  = s2 * (1.0f / 512.0f) - mean * mean;
    float rstd = rsqrtf(var + 1e-5f);
    float y0 = (v0 - mean) * rstd * g[tid]       + bb[tid];
    float y1 = (v1 - mean) * rstd * g[tid + 256] + bb[tid + 256];
    x[base + tid]        = y0;
    x[base + tid + 256]  = y1;
    xb[base + tid]       = (__bf16)y0;
    xb[base + tid + 256] = (__bf16)y1;
}

// ---------------------------------------------------------------- launch
extern "C" void kernel_launch(void* const* d_in, const int* in_sizes, int n_in,
                              void* d_out, int out_size, void* d_ws, size_t ws_size,
                              hipStream_t stream)
{
    const int*   src        = (const int*)  d_in[0];
    const int*   tgt        = (const int*)  d_in[1];
    const float* src_emb    = (const float*)d_in[2];
    const float* tgt_emb    = (const float*)d_in[3];
    const float* enc_attn_w = (const float*)d_in[4];
    const float* enc_attn_b = (const float*)d_in[5];
    const float* enc_ffn_w1 = (const float*)d_in[6];
    const float* enc_ffn_b1 = (const float*)d_in[7];
    const float* enc_ffn_w2 = (const float*)d_in[8];
    const float* enc_ffn_b2 = (const float*)d_in[9];
    const float* enc_ln_g   = (const float*)d_in[10];
    const float* enc_ln_b   = (const float*)d_in[11];
    const float* dec_self_w = (const float*)d_in[12];
    const float* dec_self_b = (const float*)d_in[13];
    const float* dec_cross_w= (const float*)d_in[14];
    const float* dec_cross_b= (const float*)d_in[15];
    const float* dec_ffn_w1 = (const float*)d_in[16];
    const float* dec_ffn_b1 = (const float*)d_in[17];
    const float* dec_ffn_w2 = (const float*)d_in[18];
    const float* dec_ffn_b2 = (const float*)d_in[19];
    const float* dec_ln_g   = (const float*)d_in[20];
    const float* dec_ln_b   = (const float*)d_in[21];
    const float* out_w      = (const float*)d_in[22];
    const float* out_b      = (const float*)d_in[23];

    const size_t NROW = (size_t)NTOK * Dm;        // 2,097,152
    const size_t NH1  = (size_t)NTOK * DFFv;      // 8,388,608

    float* ws  = (float*)d_ws;
    float* xe  = ws;            // f32 encoder stream
    float* xd  = xe + NROW;     // f32 decoder stream
    float* t0  = xd + NROW;     // f32 sublayer output (pre-LN)

    __bf16* xeb  = (__bf16*)(t0 + NROW);
    __bf16* xdb  = xeb + NROW;
    __bf16* qbb  = xdb + NROW;
    __bf16* kbb  = qbb + NROW;
    __bf16* vbT  = kbb + NROW;            // [(b*8+h)*64+f][512]
    __bf16* ctxb = vbT + NROW;
    __bf16* h1b  = ctxb + NROW;           // [4096,2048] bf16

    const size_t WSZ  = (size_t)Dm * Dm;          // 262144
    const size_t FSZ  = (size_t)Dm * DFFv;        // 1048576
    __bf16* w_enc_attn = h1b + NH1;
    __bf16* w_enc_f1   = w_enc_attn + 24 * WSZ;
    __bf16* w_enc_f2   = w_enc_f1 + 6 * FSZ;
    __bf16* w_dec_self = w_enc_f2 + 6 * FSZ;
    __bf16* w_dec_cross= w_dec_self + 24 * WSZ;
    __bf16* w_dec_f1   = w_dec_cross + 24 * WSZ;
    __bf16* w_dec_f2   = w_dec_f1 + 6 * FSZ;
    __bf16* w_out      = w_dec_f2 + 6 * FSZ;      // 512*32000

    // ---- weight transpose+convert
    wtr_k<<<dim3(Dm / 32, Dm / 32, 24), 256, 0, stream>>>(enc_attn_w, w_enc_attn, Dm, Dm);
    wtr_k<<<dim3(DFFv / 32, Dm / 32, 6), 256, 0, stream>>>(enc_ffn_w1, w_enc_f1, Dm, DFFv);
    wtr_k<<<dim3(Dm / 32, DFFv / 32, 6), 256, 0, stream>>>(enc_ffn_w2, w_enc_f2, DFFv, Dm);
    wtr_k<<<dim3(Dm / 32, Dm / 32, 24), 256, 0, stream>>>(dec_self_w, w_dec_self, Dm, Dm);
    wtr_k<<<dim3(Dm / 32, Dm / 32, 24), 256, 0, stream>>>(dec_cross_w, w_dec_cross, Dm, Dm);
    wtr_k<<<dim3(DFFv / 32, Dm / 32, 6), 256, 0, stream>>>(dec_ffn_w1, w_dec_f1, Dm, DFFv);
    wtr_k<<<dim3(Dm / 32, DFFv / 32, 6), 256, 0, stream>>>(dec_ffn_w2, w_dec_f2, DFFv, Dm);
    wtr_k<<<dim3(Vv / 32, Dm / 32, 1), 256, 0, stream>>>(out_w, w_out, Dm, Vv);

    auto gqkv = [&](const __bf16* A, const __bf16* Wt, const float* bias) {
        gemm_mfma_k<64, 128, 0, 2, 0><<<dim3(1536 / 128, NTOK / 64), 256, 0, stream>>>(
            A, Wt, bias, qbb, kbb, vbT, NTOK, 1536, Dm);
    };
    auto gkv = [&](const __bf16* A, const __bf16* Wt, const float* bias) {
        gemm_mfma_k<64, 128, 0, 3, 0><<<dim3(1024 / 128, NTOK / 64), 256, 0, stream>>>(
            A, Wt, bias, kbb, nullptr, vbT, NTOK, 1024, Dm);
    };
    auto g64f = [&](const __bf16* A, const __bf16* Wt, const float* bias, float* C, int K) {
        gemm_mfma_k<64, 64, 0, 0, 0><<<dim3(Dm / 64, NTOK / 64), 256, 0, stream>>>(
            A, Wt, bias, C, nullptr, nullptr, NTOK, Dm, K);
    };
    auto g64b = [&](const __bf16* A, const __bf16* Wt, const float* bias, __bf16* C, int K) {
        gemm_mfma_k<64, 64, 0, 1, 0><<<dim3(Dm / 64, NTOK / 64), 256, 0, stream>>>(
            A, Wt, bias, C, nullptr, nullptr, NTOK, Dm, K);
    };
    auto attn = [&](const __bf16* Q, const __bf16* K, const __bf16* Vt, __bf16* O,
                    const int* kt, int causal) {
        attn_mfma_k<<<dim3(Ss / 64, Hh, Bb), 256, 0, stream>>>(Q, K, Vt, O, kt, causal);
    };
    auto lnorm = [&](float* x, const float* a, const float* g, const float* b, __bf16* xb) {
        add_ln_k<<<NTOK, 256, 0, stream>>>(x, a, g, b, xb);
    };

    // embeddings + PE
    embed_pe_k<<<NTOK, 256, 0, stream>>>(src, src_emb, xe, xeb, Ss);
    embed_pe_k<<<NTOK, 256, 0, stream>>>(tgt, tgt_emb, xd, xdb, Ss);

    // ---------------- encoder
    for (int i = 0; i < Ll; ++i) {
        const __bf16* W = w_enc_attn + (size_t)i * 4 * WSZ;
        const float* Bv = enc_attn_b + (size_t)i * 4 * Dm;
        gqkv(xeb, W, Bv);                               // q,k,v (+V transposed)
        attn(qbb, kbb, vbT, ctxb, src, 0);
        g64f(ctxb, W + 3 * WSZ, Bv + 3 * Dm, t0, Dm);
        lnorm(xe, t0, enc_ln_g + i * 2 * Dm, enc_ln_b + i * 2 * Dm, xeb);
        gemm_mfma_k<128, 128, 1, 1, 0><<<dim3(DFFv / 128, NTOK / 128), 256, 0, stream>>>(
            xeb, w_enc_f1 + (size_t)i * FSZ, enc_ffn_b1 + i * DFFv, h1b, nullptr, nullptr,
            NTOK, DFFv, Dm);
        g64f(h1b, w_enc_f2 + (size_t)i * FSZ, enc_ffn_b2 + i * Dm, t0, DFFv);
        lnorm(xe, t0, enc_ln_g + i * 2 * Dm + Dm, enc_ln_b + i * 2 * Dm + Dm, xeb);
    }

    // ---------------- decoder
    for (int i = 0; i < Ll; ++i) {
        const __bf16* Wsf = w_dec_self + (size_t)i * 4 * WSZ;
        const float* Bsf = dec_self_b + (size_t)i * 4 * Dm;
        gqkv(xdb, Wsf, Bsf);
        attn(qbb, kbb, vbT, ctxb, tgt, 1);                   // causal + tgt pad
        g64f(ctxb, Wsf + 3 * WSZ, Bsf + 3 * Dm, t0, Dm);
        lnorm(xd, t0, dec_ln_g + i * 3 * Dm, dec_ln_b + i * 3 * Dm, xdb);

        const __bf16* Wc = w_dec_cross + (size_t)i * 4 * WSZ;
        const float* Bc = dec_cross_b + (size_t)i * 4 * Dm;
        g64b(xdb, Wc + 0 * WSZ, Bc + 0 * Dm, qbb, Dm);       // Q from decoder
        gkv(xeb, Wc + 1 * WSZ, Bc + 1 * Dm);                 // K,V from encoder memory
        attn(qbb, kbb, vbT, ctxb, src, 0);                   // src pad
        g64f(ctxb, Wc + 3 * WSZ, Bc + 3 * Dm, t0, Dm);
        lnorm(xd, t0, dec_ln_g + i * 3 * Dm + Dm, dec_ln_b + i * 3 * Dm + Dm, xdb);

        gemm_mfma_k<128, 128, 1, 1, 0><<<dim3(DFFv / 128, NTOK / 128), 256, 0, stream>>>(
            xdb, w_dec_f1 + (size_t)i * FSZ, dec_ffn_b1 + i * DFFv, h1b, nullptr, nullptr,
            NTOK, DFFv, Dm);
        g64f(h1b, w_dec_f2 + (size_t)i * FSZ, dec_ffn_b2 + i * Dm, t0, DFFv);
        lnorm(xd, t0, dec_ln_g + i * 3 * Dm + 2 * Dm, dec_ln_b + i * 3 * Dm + 2 * Dm, xdb);
    }

    // ---------------- final vocab projection -> d_out [8,512,32000] f32
    // M-fastest grid: 32 consecutive blocks share one 256KB weight panel (L2-resident)
    gemm_mfma_k<128, 256, 0, 0, 1><<<dim3(NTOK / 128, Vv / 256), 256, 0, stream>>>(
        xdb, w_out, out_b, d_out, nullptr, nullptr, NTOK, Vv, Dm);
}

// Round 7
// 2129.586 us; speedup vs baseline: 11.8744x; 1.0995x over previous
//
#include <hip/hip_runtime.h>
#include <hip/hip_bf16.h>

// TransformerNMT r6: BK=64 everywhere, XOR-swizzled GEMM LDS (both sides),
// 256^2 8-wave 2-phase vocab GEMM. MFMA flash attention unchanged.
// B=8, S=T=512, D=512, H=8, hd=64, L=6, DFF=2048, V=32000, PAD=0

#define Dm 512
#define Hh 8
#define HD 64
#define Ll 6
#define DFFv 2048
#define Vv 32000
#define Bb 8
#define Ss 512
#define NTOK (Bb * Ss)   // 4096 rows

typedef __bf16 bf16x8 __attribute__((ext_vector_type(8)));
typedef __bf16 bf16x4 __attribute__((ext_vector_type(4)));
typedef float  f32x4  __attribute__((ext_vector_type(4)));

#define GLOAD16(gp, lp) __builtin_amdgcn_global_load_lds( \
    (const __attribute__((address_space(1))) unsigned int*)(const void*)(gp), \
    (__attribute__((address_space(3))) unsigned int*)(void*)(lp), 16, 0, 0)

// ---------------------------------------------------------------- embed + PE (f32 + bf16 out)
__global__ void embed_pe_k(const int* __restrict__ tok, const float* __restrict__ emb,
                           float* __restrict__ out, __bf16* __restrict__ outb, int Slen)
{
    int row = blockIdx.x;
    int s = row % Slen;
    int t = tok[row];
    const float* e = emb + (size_t)t * Dm;
    float* o = out + (size_t)row * Dm;
    __bf16* ob = outb + (size_t)row * Dm;
    for (int dd = threadIdx.x; dd < Dm; dd += blockDim.x) {
        int j = dd >> 1;
        float div = expf((float)(2 * j) * (-9.210340371976184f / 512.0f));
        float ang = (float)s * div;
        float pe = (dd & 1) ? cosf(ang) : sinf(ang);
        float v = e[dd] * 22.627416997969522f + pe;   // sqrt(512)
        o[dd] = v;
        ob[dd] = (__bf16)v;
    }
}

// ---------------------------------------------------------------- weight transpose+convert
__global__ __launch_bounds__(256) void wtr_k(const float* __restrict__ W,
                                             __bf16* __restrict__ Wt, int K, int N)
{
    __shared__ float t[32][33];
    size_t msz = (size_t)K * N;
    const float* Wm = W + (size_t)blockIdx.z * msz;
    __bf16* Wtm = Wt + (size_t)blockIdx.z * msz;
    int n0 = blockIdx.x * 32, k0 = blockIdx.y * 32;
    int r = threadIdx.x >> 3, c4 = (threadIdx.x & 7) * 4;
    float4 v = *reinterpret_cast<const float4*>(&Wm[(size_t)(k0 + r) * N + n0 + c4]);
    t[r][c4] = v.x; t[r][c4 + 1] = v.y; t[r][c4 + 2] = v.z; t[r][c4 + 3] = v.w;
    __syncthreads();
    int n = threadIdx.x >> 3, kq = (threadIdx.x & 7) * 4;
    bf16x4 o;
    o[0] = (__bf16)t[kq + 0][n]; o[1] = (__bf16)t[kq + 1][n];
    o[2] = (__bf16)t[kq + 2][n]; o[3] = (__bf16)t[kq + 3][n];
    *reinterpret_cast<bf16x4*>(&Wtm[(size_t)(n0 + n) * K + k0 + kq]) = o;
}

// ---------------------------------------------------------------- MFMA GEMM (4 waves, BK=64)
// C[M,N] = A[M,K](bf16) @ Wt[N,K](bf16)^T + bias. LDS rows are 64 k = 128 B,
// XOR-swizzled (16B chunk cs at row r holds global chunk cs^(r&7)).
// MODE 0: f32 out; MODE 1: bf16 out (+RELU); MODE 2: fused QKV (N=1536);
// MODE 3: fused KV (N=1024). vT: [((b*8+h)*64+f)*512 + s].
template<int BM, int BN, int RELU, int MODE>
__global__ __launch_bounds__(256) void gemm_mfma_k(const __bf16* __restrict__ A,
                                                   const __bf16* __restrict__ Wt,
                                                   const float* __restrict__ bias,
                                                   void* __restrict__ Cout,
                                                   __bf16* __restrict__ out_k,
                                                   __bf16* __restrict__ out_vT,
                                                   int M, int N, int K)
{
    constexpr int NF_M = BM / 32;
    constexpr int NF_N = BN / 32;
    __shared__ __bf16 As[2][BM * 64];
    __shared__ __bf16 Bs[2][BN * 64];
    const int tid = threadIdx.x;
    const int wave = tid >> 6, lane = tid & 63;
    const int wr = wave >> 1, wc = wave & 1;
    const int row0 = blockIdx.y * BM, col0 = blockIdx.x * BN;

    f32x4 acc[NF_M][NF_N] = {};

    const int fr = lane & 15;
    const int kg = lane >> 4;

    auto stage = [&](int buf, int k0) {
        #pragma unroll
        for (int cc = 0; cc < BM / 32; ++cc) {
            int g = cc * 256 + tid;
            int r = g >> 3, cs = g & 7, gs = cs ^ (r & 7);
            GLOAD16(A + (size_t)(row0 + r) * K + k0 + gs * 8, &As[buf][g * 8]);
        }
        #pragma unroll
        for (int cc = 0; cc < BN / 32; ++cc) {
            int g = cc * 256 + tid;
            int r = g >> 3, cs = g & 7, gs = cs ^ (r & 7);
            GLOAD16(Wt + (size_t)(col0 + r) * K + k0 + gs * 8, &Bs[buf][g * 8]);
        }
    };

    stage(0, 0);
    __syncthreads();                     // drains vmcnt -> tile 0 ready

    const int nk = K >> 6;
    for (int kb = 0; kb < nk; ++kb) {
        int cur = kb & 1;
        if (kb + 1 < nk) stage(cur ^ 1, (kb + 1) * 64);   // prefetch in flight

        const char* Ab = (const char*)As[cur];
        const char* Bbp = (const char*)Bs[cur];
        #pragma unroll
        for (int ks = 0; ks < 2; ++ks) {
            bf16x8 af[NF_M], bq[NF_N];
            #pragma unroll
            for (int m = 0; m < NF_M; ++m) {
                int ar = wr * (BM / 2) + m * 16 + fr;
                af[m] = *reinterpret_cast<const bf16x8*>(
                    Ab + ar * 128 + (((ks * 4 + kg) ^ (ar & 7)) << 4));
            }
            #pragma unroll
            for (int n = 0; n < NF_N; ++n) {
                int br = wc * (BN / 2) + n * 16 + fr;
                bq[n] = *reinterpret_cast<const bf16x8*>(
                    Bbp + br * 128 + (((ks * 4 + kg) ^ (br & 7)) << 4));
            }
            #pragma unroll
            for (int m = 0; m < NF_M; ++m)
                #pragma unroll
                for (int n = 0; n < NF_N; ++n)
                    acc[m][n] = __builtin_amdgcn_mfma_f32_16x16x32_bf16(
                        af[m], bq[n], acc[m][n], 0, 0, 0);
        }
        __syncthreads();                 // prefetch drained + reads done
    }

    #pragma unroll
    for (int m = 0; m < NF_M; ++m) {
        #pragma unroll
        for (int n = 0; n < NF_N; ++n) {
            int colg = col0 + wc * (BN / 2) + n * 16 + fr;
            float bv = bias[colg];
            #pragma unroll
            for (int j = 0; j < 4; ++j) {
                int row = row0 + wr * (BM / 2) + m * 16 + kg * 4 + j;
                float v = acc[m][n][j] + bv;
                if (RELU) v = fmaxf(v, 0.f);
                if constexpr (MODE == 0) {
                    ((float*)Cout)[(size_t)row * N + colg] = v;
                } else if constexpr (MODE == 1) {
                    ((__bf16*)Cout)[(size_t)row * N + colg] = (__bf16)v;
                } else {
                    int seg = colg >> 9;          // uniform per block
                    int c = colg & 511;
                    bool isV = (MODE == 2) ? (seg == 2) : (seg == 1);
                    if (!isV) {
                        __bf16* o = (MODE == 2 && seg == 1) ? out_k : (__bf16*)Cout;
                        o[(size_t)row * 512 + c] = (__bf16)v;
                    } else {
                        int bi = row >> 9, s = row & 511;
                        int hh = c >> 6, f = c & 63;
                        out_vT[(size_t)((bi * 8 + hh) * 64 + f) * 512 + s] = (__bf16)v;
                    }
                }
            }
        }
    }
}

// ---------------------------------------------------------------- 256^2 8-wave GEMM (vocab)
// 512 threads = 8 waves (2M x 4N); tile 256x256, BK=64, dbuf (128 KB LDS),
// XOR-swizzled. M-fastest grid (blockIdx.x = M-tile). f32 out + bias.
__global__ __launch_bounds__(512) void gemm256_k(const __bf16* __restrict__ A,
                                                 const __bf16* __restrict__ Wt,
                                                 const float* __restrict__ bias,
                                                 float* __restrict__ C,
                                                 int M, int N, int K)
{
    __shared__ __bf16 As[2][256 * 64];
    __shared__ __bf16 Bs[2][256 * 64];
    const int tid = threadIdx.x;
    const int wave = tid >> 6, lane = tid & 63;
    const int wr = wave >> 2, wc = wave & 3;     // 2 x 4
    const int row0 = blockIdx.x * 256, col0 = blockIdx.y * 256;

    f32x4 acc[8][4] = {};

    const int fr = lane & 15;
    const int kg = lane >> 4;

    auto stage = [&](int buf, int k0) {
        #pragma unroll
        for (int cc = 0; cc < 4; ++cc) {
            int g = cc * 512 + tid;              // 0..2047
            int r = g >> 3, cs = g & 7, gs = cs ^ (r & 7);
            GLOAD16(A + (size_t)(row0 + r) * K + k0 + gs * 8, &As[buf][g * 8]);
        }
        #pragma unroll
        for (int cc = 0; cc < 4; ++cc) {
            int g = cc * 512 + tid;
            int r = g >> 3, cs = g & 7, gs = cs ^ (r & 7);
            GLOAD16(Wt + (size_t)(col0 + r) * K + k0 + gs * 8, &Bs[buf][g * 8]);
        }
    };

    stage(0, 0);
    __syncthreads();

    const int nk = K >> 6;
    for (int kb = 0; kb < nk; ++kb) {
        int cur = kb & 1;
        if (kb + 1 < nk) stage(cur ^ 1, (kb + 1) * 64);

        const char* Ab = (const char*)As[cur];
        const char* Bbp = (const char*)Bs[cur];
        #pragma unroll
        for (int ks = 0; ks < 2; ++ks) {
            bf16x8 af[8], bq[4];
            #pragma unroll
            for (int m = 0; m < 8; ++m) {
                int ar = wr * 128 + m * 16 + fr;
                af[m] = *reinterpret_cast<const bf16x8*>(
                    Ab + ar * 128 + (((ks * 4 + kg) ^ (ar & 7)) << 4));
            }
            #pragma unroll
            for (int n = 0; n < 4; ++n) {
                int br = wc * 64 + n * 16 + fr;
                bq[n] = *reinterpret_cast<const bf16x8*>(
                    Bbp + br * 128 + (((ks * 4 + kg) ^ (br & 7)) << 4));
            }
            #pragma unroll
            for (int m = 0; m < 8; ++m)
                #pragma unroll
                for (int n = 0; n < 4; ++n)
                    acc[m][n] = __builtin_amdgcn_mfma_f32_16x16x32_bf16(
                        af[m], bq[n], acc[m][n], 0, 0, 0);
        }
        __syncthreads();
    }

    #pragma unroll
    for (int m = 0; m < 8; ++m) {
        #pragma unroll
        for (int n = 0; n < 4; ++n) {
            int colg = col0 + wc * 64 + n * 16 + fr;
            float bv = bias[colg];
            #pragma unroll
            for (int j = 0; j < 4; ++j) {
                int row = row0 + wr * 128 + m * 16 + kg * 4 + j;
                C[(size_t)row * N + colg] = acc[m][n][j] + bv;
            }
        }
    }
}

// ---------------------------------------------------------------- MFMA flash attention
// KVBLK=128, double-buffered K/V staging (one barrier per tile).
__global__ __launch_bounds__(256) void attn_mfma_k(const __bf16* __restrict__ Qb,
                                                   const __bf16* __restrict__ Kb,
                                                   const __bf16* __restrict__ VbT,
                                                   __bf16* __restrict__ Ob,
                                                   const int* __restrict__ key_tok,
                                                   int causal)
{
    __shared__ __bf16 Ks[2][128 * 64];     // [key][feat], 128B rows, swizzled
    __shared__ __bf16 Vs[2][64 * 128];     // [feat][key], 256B rows, swizzled
    __shared__ __bf16 Pl[4][16 * 128];     // per-wave P, 256B rows, swizzled

    const int tid = threadIdx.x;
    const int w = tid >> 6, lane = tid & 63;
    const int fr = lane & 15, kg = lane >> 4;
    const int q0 = blockIdx.x * 64;
    const int h = blockIdx.y, b = blockIdx.z;
    const int qrow = q0 + w * 16 + fr;
    const int swz = (fr & 7) << 4;

    bf16x8 qf[2];
    {
        const __bf16* qp = Qb + ((size_t)(b * 512 + qrow) * 512 + h * 64 + kg * 8);
        qf[0] = *reinterpret_cast<const bf16x8*>(qp);
        qf[1] = *reinterpret_cast<const bf16x8*>(qp + 32);
    }

    f32x4 po[4] = {};
    float m_run = -3.0e38f, l_run = 0.f;
    __bf16* pw = Pl[w];

    auto stage = [&](int buf, int kk0) {
        #pragma unroll
        for (int c = 0; c < 4; ++c) {
            int ch = c * 256 + tid;               // 0..1023 (16B groups)
            int r = ch >> 3, gsk = (ch & 7) ^ (r & 7);
            GLOAD16(Kb + ((size_t)(b * 512 + kk0 + r) * 512 + h * 64 + gsk * 8),
                    &Ks[buf][ch * 8]);
            int f = ch >> 4, gsv = (ch & 15) ^ (f & 7);
            GLOAD16(VbT + ((size_t)((b * 8 + h) * 64 + f) * 512 + kk0 + gsv * 8),
                    &Vs[buf][ch * 8]);
        }
    };

    const int kkend = causal ? ((q0 + 64 + 127) & ~127) : 512;
    stage(0, 0);
    __syncthreads();

    for (int kk0 = 0; kk0 < kkend; kk0 += 128) {
        int cur = (kk0 >> 7) & 1;
        if (kk0 + 128 < kkend) stage(cur ^ 1, kk0 + 128);   // prefetch in flight

        unsigned long long vm0 = __ballot(key_tok[b * 512 + kk0 + lane] != 0);
        unsigned long long vm1 = __ballot(key_tok[b * 512 + kk0 + 64 + lane] != 0);

        // ---- S^T = K @ Q^T
        f32x4 st[8];
        #pragma unroll
        for (int kt = 0; kt < 8; ++kt) {
            f32x4 s = {};
            #pragma unroll
            for (int ks = 0; ks < 2; ++ks) {
                int byte = ((kt * 16 + fr) * 128 + ks * 64 + kg * 16) ^ swz;
                bf16x8 kf = *reinterpret_cast<const bf16x8*>((const char*)Ks[cur] + byte);
                s = __builtin_amdgcn_mfma_f32_16x16x32_bf16(kf, qf[ks], s, 0, 0, 0);
            }
            st[kt] = s;
        }

        // ---- mask + online softmax
        float sv[8][4];
        float mloc = -3.0e38f;
        #pragma unroll
        for (int kt = 0; kt < 8; ++kt) {
            unsigned long long vm = (kt < 4) ? vm0 : vm1;
            #pragma unroll
            for (int j = 0; j < 4; ++j) {
                int kl = kt * 16 + kg * 4 + j;
                float s = st[kt][j] * 0.125f;
                bool ok = (vm >> (kl & 63)) & 1ull;
                if (causal && (kk0 + kl > qrow)) ok = false;
                s = ok ? s : -1e9f;
                sv[kt][j] = s;
                mloc = fmaxf(mloc, s);
            }
        }
        mloc = fmaxf(mloc, __shfl_xor(mloc, 16));
        mloc = fmaxf(mloc, __shfl_xor(mloc, 32));
        float m_new = fmaxf(m_run, mloc);
        float scale = __expf(m_run - m_new);
        float ls = 0.f;
        #pragma unroll
        for (int kt = 0; kt < 8; ++kt)
            #pragma unroll
            for (int j = 0; j < 4; ++j) {
                float p = __expf(sv[kt][j] - m_new);
                sv[kt][j] = p;
                ls += p;
            }
        ls += __shfl_xor(ls, 16);
        ls += __shfl_xor(ls, 32);
        l_run = l_run * scale + ls;
        m_run = m_new;

        // ---- P -> per-wave LDS (256B rows, swizzled)
        #pragma unroll
        for (int kt = 0; kt < 8; ++kt)
            #pragma unroll
            for (int c = 0; c < 2; ++c) {
                union { __bf16 hh[2]; unsigned u; } pk;
                pk.hh[0] = (__bf16)sv[kt][2 * c];
                pk.hh[1] = (__bf16)sv[kt][2 * c + 1];
                int byte = (fr * 256 + kt * 32 + kg * 8 + c * 4) ^ swz;
                *reinterpret_cast<unsigned*>((char*)pw + byte) = pk.u;
            }

        // ---- rescale O
        {
            int qb4 = kg * 4;
            float s0 = __shfl(scale, qb4 + 0), s1 = __shfl(scale, qb4 + 1);
            float s2 = __shfl(scale, qb4 + 2), s3 = __shfl(scale, qb4 + 3);
            #pragma unroll
            for (int nf = 0; nf < 4; ++nf) {
                po[nf][0] *= s0; po[nf][1] *= s1;
                po[nf][2] *= s2; po[nf][3] *= s3;
            }
        }

        // ---- PV: O += P @ V
        #pragma unroll
        for (int ks2 = 0; ks2 < 4; ++ks2) {
            int pbyte = (fr * 256 + ks2 * 64 + kg * 16) ^ swz;
            bf16x8 pa = *reinterpret_cast<const bf16x8*>((const char*)pw + pbyte);
            #pragma unroll
            for (int nf = 0; nf < 4; ++nf) {
                int vbyte = ((nf * 16 + fr) * 256 + ks2 * 64 + kg * 16) ^ swz;
                bf16x8 vf = *reinterpret_cast<const bf16x8*>((const char*)Vs[cur] + vbyte);
                po[nf] = __builtin_amdgcn_mfma_f32_16x16x32_bf16(pa, vf, po[nf], 0, 0, 0);
            }
        }
        __syncthreads();                 // prefetch drained + Ks/Vs reads done
    }

    {
        int qb4 = kg * 4;
        float r0 = 1.0f / __shfl(l_run, qb4 + 0);
        float r1 = 1.0f / __shfl(l_run, qb4 + 1);
        float r2 = 1.0f / __shfl(l_run, qb4 + 2);
        float r3 = 1.0f / __shfl(l_run, qb4 + 3);
        #pragma unroll
        for (int nf = 0; nf < 4; ++nf) {
            size_t base = (size_t)(b * 512 + q0 + w * 16 + qb4) * 512 + h * 64 + nf * 16 + fr;
            Ob[base]           = (__bf16)(po[nf][0] * r0);
            Ob[base + 512]     = (__bf16)(po[nf][1] * r1);
            Ob[base + 1024]    = (__bf16)(po[nf][2] * r2);
            Ob[base + 1536]    = (__bf16)(po[nf][3] * r3);
        }
    }
}

// ---------------------------------------------------------------- residual + LN (+ bf16 copy)
__global__ __launch_bounds__(256) void add_ln_k(float* __restrict__ x,
                                                const float* __restrict__ a,
                                                const float* __restrict__ g,
                                                const float* __restrict__ bb,
                                                __bf16* __restrict__ xb)
{
    int row = blockIdx.x;
    size_t base = (size_t)row * Dm;
    int tid = threadIdx.x;
    float v0 = x[base + tid]       + a[base + tid];
    float v1 = x[base + tid + 256] + a[base + tid + 256];
    float s  = v0 + v1;
    float s2 = v0 * v0 + v1 * v1;
    #pragma unroll
    for (int o = 1; o < 64; o <<= 1) {
        s  += __shfl_xor(s, o);
        s2 += __shfl_xor(s2, o);
    }
    __shared__ float red[8];
    int wid = tid >> 6, lane = tid & 63;
    if (lane == 0) { red[wid] = s; red[wid + 4] = s2; }
    __syncthreads();
    s  = red[0] + red[1] + red[2] + red[3];
    s2 = red[4] + red[5] + red[6] + red[7];
    float mean = s * (1.0f / 512.0f);
    float var  = s2 * (1.0f / 512.0f) - mean * mean;
    float rstd = rsqrtf(var + 1e-5f);
    float y0 = (v0 - mean) * rstd * g[tid]       + bb[tid];
    float y1 = (v1 - mean) * rstd * g[tid + 256] + bb[tid + 256];
    x[base + tid]        = y0;
    x[base + tid + 256]  = y1;
    xb[base + tid]       = (__bf16)y0;
    xb[base + tid + 256] = (__bf16)y1;
}

// ---------------------------------------------------------------- launch
extern "C" void kernel_launch(void* const* d_in, const int* in_sizes, int n_in,
                              void* d_out, int out_size, void* d_ws, size_t ws_size,
                              hipStream_t stream)
{
    const int*   src        = (const int*)  d_in[0];
    const int*   tgt        = (const int*)  d_in[1];
    const float* src_emb    = (const float*)d_in[2];
    const float* tgt_emb    = (const float*)d_in[3];
    const float* enc_attn_w = (const float*)d_in[4];
    const float* enc_attn_b = (const float*)d_in[5];
    const float* enc_ffn_w1 = (const float*)d_in[6];
    const float* enc_ffn_b1 = (const float*)d_in[7];
    const float* enc_ffn_w2 = (const float*)d_in[8];
    const float* enc_ffn_b2 = (const float*)d_in[9];
    const float* enc_ln_g   = (const float*)d_in[10];
    const float* enc_ln_b   = (const float*)d_in[11];
    const float* dec_self_w = (const float*)d_in[12];
    const float* dec_self_b = (const float*)d_in[13];
    const float* dec_cross_w= (const float*)d_in[14];
    const float* dec_cross_b= (const float*)d_in[15];
    const float* dec_ffn_w1 = (const float*)d_in[16];
    const float* dec_ffn_b1 = (const float*)d_in[17];
    const float* dec_ffn_w2 = (const float*)d_in[18];
    const float* dec_ffn_b2 = (const float*)d_in[19];
    const float* dec_ln_g   = (const float*)d_in[20];
    const float* dec_ln_b   = (const float*)d_in[21];
    const float* out_w      = (const float*)d_in[22];
    const float* out_b      = (const float*)d_in[23];

    const size_t NROW = (size_t)NTOK * Dm;        // 2,097,152
    const size_t NH1  = (size_t)NTOK * DFFv;      // 8,388,608

    float* ws  = (float*)d_ws;
    float* xe  = ws;            // f32 encoder stream
    float* xd  = xe + NROW;     // f32 decoder stream
    float* t0  = xd + NROW;     // f32 sublayer output (pre-LN)

    __bf16* xeb  = (__bf16*)(t0 + NROW);
    __bf16* xdb  = xeb + NROW;
    __bf16* qbb  = xdb + NROW;
    __bf16* kbb  = qbb + NROW;
    __bf16* vbT  = kbb + NROW;            // [(b*8+h)*64+f][512]
    __bf16* ctxb = vbT + NROW;
    __bf16* h1b  = ctxb + NROW;           // [4096,2048] bf16

    const size_t WSZ  = (size_t)Dm * Dm;          // 262144
    const size_t FSZ  = (size_t)Dm * DFFv;        // 1048576
    __bf16* w_enc_attn = h1b + NH1;
    __bf16* w_enc_f1   = w_enc_attn + 24 * WSZ;
    __bf16* w_enc_f2   = w_enc_f1 + 6 * FSZ;
    __bf16* w_dec_self = w_enc_f2 + 6 * FSZ;
    __bf16* w_dec_cross= w_dec_self + 24 * WSZ;
    __bf16* w_dec_f1   = w_dec_cross + 24 * WSZ;
    __bf16* w_dec_f2   = w_dec_f1 + 6 * FSZ;
    __bf16* w_out      = w_dec_f2 + 6 * FSZ;      // 512*32000

    // ---- weight transpose+convert
    wtr_k<<<dim3(Dm / 32, Dm / 32, 24), 256, 0, stream>>>(enc_attn_w, w_enc_attn, Dm, Dm);
    wtr_k<<<dim3(DFFv / 32, Dm / 32, 6), 256, 0, stream>>>(enc_ffn_w1, w_enc_f1, Dm, DFFv);
    wtr_k<<<dim3(Dm / 32, DFFv / 32, 6), 256, 0, stream>>>(enc_ffn_w2, w_enc_f2, DFFv, Dm);
    wtr_k<<<dim3(Dm / 32, Dm / 32, 24), 256, 0, stream>>>(dec_self_w, w_dec_self, Dm, Dm);
    wtr_k<<<dim3(Dm / 32, Dm / 32, 24), 256, 0, stream>>>(dec_cross_w, w_dec_cross, Dm, Dm);
    wtr_k<<<dim3(DFFv / 32, Dm / 32, 6), 256, 0, stream>>>(dec_ffn_w1, w_dec_f1, Dm, DFFv);
    wtr_k<<<dim3(Dm / 32, DFFv / 32, 6), 256, 0, stream>>>(dec_ffn_w2, w_dec_f2, DFFv, Dm);
    wtr_k<<<dim3(Vv / 32, Dm / 32, 1), 256, 0, stream>>>(out_w, w_out, Dm, Vv);

    auto gqkv = [&](const __bf16* A, const __bf16* Wt, const float* bias) {
        gemm_mfma_k<64, 128, 0, 2><<<dim3(1536 / 128, NTOK / 64), 256, 0, stream>>>(
            A, Wt, bias, qbb, kbb, vbT, NTOK, 1536, Dm);
    };
    auto gkv = [&](const __bf16* A, const __bf16* Wt, const float* bias) {
        gemm_mfma_k<64, 128, 0, 3><<<dim3(1024 / 128, NTOK / 64), 256, 0, stream>>>(
            A, Wt, bias, kbb, nullptr, vbT, NTOK, 1024, Dm);
    };
    auto g64f = [&](const __bf16* A, const __bf16* Wt, const float* bias, float* C, int K) {
        gemm_mfma_k<64, 64, 0, 0><<<dim3(Dm / 64, NTOK / 64), 256, 0, stream>>>(
            A, Wt, bias, C, nullptr, nullptr, NTOK, Dm, K);
    };
    auto attn = [&](const __bf16* Q, const __bf16* K, const __bf16* Vt, __bf16* O,
                    const int* kt, int causal) {
        attn_mfma_k<<<dim3(Ss / 64, Hh, Bb), 256, 0, stream>>>(Q, K, Vt, O, kt, causal);
    };
    auto lnorm = [&](float* x, const float* a, const float* g, const float* b, __bf16* xb) {
        add_ln_k<<<NTOK, 256, 0, stream>>>(x, a, g, b, xb);
    };

    // embeddings + PE
    embed_pe_k<<<NTOK, 256, 0, stream>>>(src, src_emb, xe, xeb, Ss);
    embed_pe_k<<<NTOK, 256, 0, stream>>>(tgt, tgt_emb, xd, xdb, Ss);

    // ---------------- encoder
    for (int i = 0; i < Ll; ++i) {
        const __bf16* W = w_enc_attn + (size_t)i * 4 * WSZ;
        const float* Bv = enc_attn_b + (size_t)i * 4 * Dm;
        gqkv(xeb, W, Bv);                               // q,k,v (+V transposed)
        attn(qbb, kbb, vbT, ctxb, src, 0);
        g64f(ctxb, W + 3 * WSZ, Bv + 3 * Dm, t0, Dm);
        lnorm(xe, t0, enc_ln_g + i * 2 * Dm, enc_ln_b + i * 2 * Dm, xeb);
        gemm_mfma_k<128, 128, 1, 1><<<dim3(DFFv / 128, NTOK / 128), 256, 0, stream>>>(
            xeb, w_enc_f1 + (size_t)i * FSZ, enc_ffn_b1 + i * DFFv, h1b, nullptr, nullptr,
            NTOK, DFFv, Dm);
        g64f(h1b, w_enc_f2 + (size_t)i * FSZ, enc_ffn_b2 + i * Dm, t0, DFFv);
        lnorm(xe, t0, enc_ln_g + i * 2 * Dm + Dm, enc_ln_b + i * 2 * Dm + Dm, xeb);
    }

    // ---------------- decoder
    for (int i = 0; i < Ll; ++i) {
        const __bf16* Wsf = w_dec_self + (size_t)i * 4 * WSZ;
        const float* Bsf = dec_self_b + (size_t)i * 4 * Dm;
        gqkv(xdb, Wsf, Bsf);
        attn(qbb, kbb, vbT, ctxb, tgt, 1);                   // causal + tgt pad
        g64f(ctxb, Wsf + 3 * WSZ, Bsf + 3 * Dm, t0, Dm);
        lnorm(xd, t0, dec_ln_g + i * 3 * Dm, dec_ln_b + i * 3 * Dm, xdb);

        const __bf16* Wc = w_dec_cross + (size_t)i * 4 * WSZ;
        const float* Bc = dec_cross_b + (size_t)i * 4 * Dm;
        gemm_mfma_k<64, 64, 0, 1><<<dim3(Dm / 64, NTOK / 64), 256, 0, stream>>>(
            xdb, Wc + 0 * WSZ, Bc + 0 * Dm, qbb, nullptr, nullptr, NTOK, Dm, Dm);
        gkv(xeb, Wc + 1 * WSZ, Bc + 1 * Dm);                 // K,V from encoder memory
        attn(qbb, kbb, vbT, ctxb, src, 0);                   // src pad
        g64f(ctxb, Wc + 3 * WSZ, Bc + 3 * Dm, t0, Dm);
        lnorm(xd, t0, dec_ln_g + i * 3 * Dm + Dm, dec_ln_b + i * 3 * Dm + Dm, xdb);

        gemm_mfma_k<128, 128, 1, 1><<<dim3(DFFv / 128, NTOK / 128), 256, 0, stream>>>(
            xdb, w_dec_f1 + (size_t)i * FSZ, dec_ffn_b1 + i * DFFv, h1b, nullptr, nullptr,
            NTOK, DFFv, Dm);
        g64f(h1b, w_dec_f2 + (size_t)i * FSZ, dec_ffn_b2 + i * Dm, t0, DFFv);
        lnorm(xd, t0, dec_ln_g + i * 3 * Dm + 2 * Dm, dec_ln_b + i * 3 * Dm + 2 * Dm, xdb);
    }

    // ---------------- final vocab projection -> d_out [8,512,32000] f32
    // 256^2 8-wave tile, M-fastest grid (16 M-tiles share W panels in L2/L3)
    gemm256_k<<<dim3(NTOK / 256, Vv / 256), 512, 0, stream>>>(
        xdb, w_out, out_b, (float*)d_out, NTOK, Vv, Dm);
}